// Round 5
// baseline (16823.470 us; speedup 1.0000x reference)
//
#include <hip/hip_runtime.h>
#include <hip/hip_bf16.h>

typedef __bf16 bfx8 __attribute__((ext_vector_type(8)));
typedef __bf16 bfx4 __attribute__((ext_vector_type(4)));
typedef float f32x4 __attribute__((ext_vector_type(4)));

#define MFMA __builtin_amdgcn_mfma_f32_16x16x32_bf16

// Dims: S=32 T=32 B=512 H=1024 E=256 A=1024 VS=64 VT=70 START=1
// Float tensors f32 in/out; MFMA on bf16 copies; h carried f32 in registers.

__device__ __attribute__((aligned(256))) float  g_h[512 * 1024];
__device__ __attribute__((aligned(256))) float  g_hpart[512 * 1024];
__device__ __attribute__((aligned(256))) __bf16 g_hb[2][512 * 1024];
__device__ __attribute__((aligned(256))) __bf16 g_Adec[512 * 1280];
__device__ __attribute__((aligned(256))) __bf16 g_enc_ops[(size_t)32 * 512 * 1024];
__device__ __attribute__((aligned(256))) __bf16 g_enc_part[(size_t)32 * 512 * 1024];
__device__ __attribute__((aligned(256))) __bf16 g_WattnT[(size_t)1024 * 2048];
__device__ __attribute__((aligned(256))) __bf16 g_Whhe[3072 * 1024];
__device__ __attribute__((aligned(256))) __bf16 g_Wihe[3072 * 256];
__device__ __attribute__((aligned(256))) __bf16 g_Whhd[3072 * 1024];
__device__ __attribute__((aligned(256))) __bf16 g_Wihd[3072 * 1280];
__device__ __attribute__((aligned(256))) __bf16 g_WoutT[128 * 1024];
__device__ __attribute__((aligned(256))) __bf16 g_embs[64 * 256];
__device__ __attribute__((aligned(256))) __bf16 g_embt[70 * 256];
__device__ int g_bar_arr[2];
__device__ int g_bar_gen[2];

__device__ __forceinline__ float fast_tanh(float x) {
    float cx = fminf(fmaxf(x, -15.f), 15.f);
    float e = __expf(-2.f * cx);
    return (1.f - e) / (1.f + e);
}

// Device-scope grid barrier (sense via generation counter). All nb blocks
// must be co-resident (enforced via LDS/launch_bounds occupancy).
__device__ __forceinline__ void grid_sync(int which, int nb) {
    __syncthreads();
    if (threadIdx.x == 0) {
        __threadfence();  // agent-scope release of prior writes
        int gen = __hip_atomic_load(&g_bar_gen[which], __ATOMIC_RELAXED,
                                    __HIP_MEMORY_SCOPE_AGENT);
        int prev = __hip_atomic_fetch_add(&g_bar_arr[which], 1, __ATOMIC_ACQ_REL,
                                          __HIP_MEMORY_SCOPE_AGENT);
        if (prev == nb - 1) {
            __hip_atomic_store(&g_bar_arr[which], 0, __ATOMIC_RELAXED,
                               __HIP_MEMORY_SCOPE_AGENT);
            __hip_atomic_fetch_add(&g_bar_gen[which], 1, __ATOMIC_RELEASE,
                                   __HIP_MEMORY_SCOPE_AGENT);
        } else {
            while (__hip_atomic_load(&g_bar_gen[which], __ATOMIC_ACQUIRE,
                                     __HIP_MEMORY_SCOPE_AGENT) == gen)
                __builtin_amdgcn_s_sleep(8);
        }
        __threadfence();  // acquire side
    }
    __syncthreads();
}

// ---------------------------------------------------------------------------
__global__ void k_cvt(const float* __restrict__ src, __bf16* __restrict__ dst,
                      int n4)
{
    int i = blockIdx.x * 256 + threadIdx.x;
    if (i >= n4) return;
    float4 v = ((const float4*)src)[i];
    __bf16 o[4] = {(__bf16)v.x, (__bf16)v.y, (__bf16)v.z, (__bf16)v.w};
    *(ushort2*)(dst + 4 * i) = *(ushort2*)o;
    *(ushort2*)(dst + 4 * i + 2) = *(ushort2*)(o + 2);
}

__global__ __launch_bounds__(256) void k_transpose(const float* __restrict__ Wsrc)
{
    __shared__ float t[32][33];
    int bx = blockIdx.x, by = blockIdx.y;
    int lx = threadIdx.x & 31, ly = threadIdx.x >> 5;
    for (int i = 0; i < 32; i += 8)
        t[ly + i][lx] = Wsrc[(size_t)(by * 32 + ly + i) * 1024 + bx * 32 + lx];
    __syncthreads();
    for (int i = 0; i < 32; i += 8)
        g_WattnT[(size_t)(bx * 32 + ly + i) * 2048 + by * 32 + lx] =
            (__bf16)t[lx][ly + i];
}

__global__ void k_cvtWout(const float* __restrict__ W)
{
    int idx = blockIdx.x * 256 + threadIdx.x;  // < 128*1024
    int c = idx >> 10, k = idx & 1023;
    g_WoutT[idx] = (__bf16)((c < 70) ? W[k * 70 + c] : 0.f);
}

__global__ void k_init(float* __restrict__ out)
{
    int idx = blockIdx.x * 256 + threadIdx.x;
    if (idx < 512 * 1024) g_hb[0][idx] = (__bf16)0.f;
    if (idx < 512 * 70) out[idx] = (idx % 70 == 1) ? 1.f : 0.f;
    if (idx < 2) { g_bar_arr[idx] = 0; g_bar_gen[idx] = 0; }
}

// ---------------------------------------------------------------------------
// Persistent encoder. 256 blocks (1/CU). Block = 16 j-cols x 128 b-rows.
// Whhe/Wihe j-slabs resident in LDS; h slice resident in registers.
// Per step: gh GEMM (K=1024) + gi GEMM (K=256, row-gather) + GRU epilogue,
// then enc_part[t] tile GEMM (blocks 0..127).
// ---------------------------------------------------------------------------
__global__ __launch_bounds__(256, 1) void enc_persistent(
    const int* __restrict__ source,
    const float* __restrict__ b1,   // b_hh_enc
    const float* __restrict__ b2)   // b_ih_enc
{
    __shared__ __bf16 sWh[48][1032];   // 99 KB
    __shared__ __bf16 sWi[48][264];    // 25 KB
    __shared__ __bf16 sA[128][40];     // 10 KB (reused by EP phase as 2x64x40)
    const int tid = threadIdx.x, bid = blockIdx.x;
    const int j0 = (bid >> 2) * 16, m0 = (bid & 3) * 128;
    const int wave = tid >> 6, lane = tid & 63;
    const int r15 = lane & 15, q = lane >> 4, kk = q * 8;
    const int arow = tid >> 1, acs = (tid & 1) * 16;

    for (int idx = tid; idx < 48 * 128; idx += 256) {
        int r = idx >> 7, ch = idx & 127;
        size_t gr = (size_t)((r >> 4) * 1024 + j0 + (r & 15));
        *(uint4*)&sWh[r][ch * 8] = *(const uint4*)&g_Whhe[gr * 1024 + ch * 8];
    }
    for (int idx = tid; idx < 48 * 32; idx += 256) {
        int r = idx >> 5, ch = idx & 31;
        size_t gr = (size_t)((r >> 4) * 1024 + j0 + (r & 15));
        *(uint4*)&sWi[r][ch * 8] = *(const uint4*)&g_Wihe[gr * 256 + ch * 8];
    }

    const int jj = j0 + r15;
    float bb1[3] = {b1[jj], b1[1024 + jj], b1[2048 + jj]};
    float bb2[3] = {b2[jj], b2[1024 + jj], b2[2048 + jj]};
    float hr[2][4] = {};
    int pp = 0;
    __syncthreads();

    for (int t = 0; t < 32; t++) {
        const __bf16* cur = g_hb[pp];
        __bf16* nxt = g_hb[pp ^ 1];
        f32x4 acc1[3][2], acc2[3][2];
#pragma unroll
        for (int s = 0; s < 3; s++)
#pragma unroll
            for (int rt = 0; rt < 2; rt++) {
                acc1[s][rt] = (f32x4){0.f, 0.f, 0.f, 0.f};
                acc2[s][rt] = (f32x4){0.f, 0.f, 0.f, 0.f};
            }
        // ---- gh = h @ Whhe^T (K=1024) ----
        {
            const __bf16* ap = cur + (size_t)(m0 + arow) * 1024 + acs;
            for (int k0 = 0; k0 < 1024; k0 += 32) {
                uint4 a0 = *(const uint4*)(ap + k0);
                uint4 a1 = *(const uint4*)(ap + k0 + 8);
                __syncthreads();
                *(uint4*)&sA[arow][acs] = a0;
                *(uint4*)&sA[arow][acs + 8] = a1;
                __syncthreads();
                bfx8 f0 = *(const bfx8*)&sA[wave * 32 + r15][kk];
                bfx8 f1 = *(const bfx8*)&sA[wave * 32 + 16 + r15][kk];
#pragma unroll
                for (int s = 0; s < 3; s++) {
                    bfx8 w = *(const bfx8*)&sWh[s * 16 + r15][k0 + kk];
                    acc1[s][0] = MFMA(f0, w, acc1[s][0], 0, 0, 0);
                    acc1[s][1] = MFMA(f1, w, acc1[s][1], 0, 0, 0);
                }
            }
        }
        // ---- gi = emb_src[source[t]] @ Wihe^T (K=256) ----
        {
            int sv = source[t * 512 + m0 + arow];
            sv = (sv < 0) ? 0 : (sv > 63 ? 63 : sv);
            const __bf16* ep = g_embs + (size_t)sv * 256 + acs;
            for (int k0 = 0; k0 < 256; k0 += 32) {
                uint4 a0 = *(const uint4*)(ep + k0);
                uint4 a1 = *(const uint4*)(ep + k0 + 8);
                __syncthreads();
                *(uint4*)&sA[arow][acs] = a0;
                *(uint4*)&sA[arow][acs + 8] = a1;
                __syncthreads();
                bfx8 f0 = *(const bfx8*)&sA[wave * 32 + r15][kk];
                bfx8 f1 = *(const bfx8*)&sA[wave * 32 + 16 + r15][kk];
#pragma unroll
                for (int s = 0; s < 3; s++) {
                    bfx8 w = *(const bfx8*)&sWi[s * 16 + r15][k0 + kk];
                    acc2[s][0] = MFMA(f0, w, acc2[s][0], 0, 0, 0);
                    acc2[s][1] = MFMA(f1, w, acc2[s][1], 0, 0, 0);
                }
            }
        }
        // ---- GRU epilogue ----
#pragma unroll
        for (int rt = 0; rt < 2; rt++) {
#pragma unroll
            for (int reg = 0; reg < 4; reg++) {
                int b_ = m0 + wave * 32 + rt * 16 + q * 4 + reg;
                float gh0 = acc1[0][rt][reg] + bb1[0];
                float gh1 = acc1[1][rt][reg] + bb1[1];
                float gh2 = acc1[2][rt][reg] + bb1[2];
                float gi0 = acc2[0][rt][reg] + bb2[0];
                float gi1 = acc2[1][rt][reg] + bb2[1];
                float gi2 = acc2[2][rt][reg] + bb2[2];
                float r = 1.f / (1.f + __expf(-(gi0 + gh0)));
                float z = 1.f / (1.f + __expf(-(gi1 + gh1)));
                float n = fast_tanh(gi2 + r * gh2);
                float hv = (1.f - z) * n + z * hr[rt][reg];
                hr[rt][reg] = hv;
                size_t off = (size_t)b_ * 1024 + jj;
                nxt[off] = (__bf16)hv;
                g_enc_ops[(size_t)t * 524288 + off] = (__bf16)hv;
            }
        }
        grid_sync(0, 256);
        // ---- EP: enc_part[t] = h_t @ W_attn[H:2H]^T (blocks 0..127) ----
        if (bid < 128) {
            const int n0e = (bid & 15) * 64, mm0 = (bid >> 4) * 64;
            const int srow = tid >> 2, scol = (tid & 3) * 8;
            f32x4 eacc[4];
#pragma unroll
            for (int n = 0; n < 4; n++) eacc[n] = (f32x4){0.f, 0.f, 0.f, 0.f};
            const __bf16* eap = nxt + (size_t)(mm0 + srow) * 1024 + scol;
            const __bf16* ewp = g_WattnT + (size_t)(n0e + srow) * 2048 + 1024 + scol;
            for (int k0 = 0; k0 < 1024; k0 += 32) {
                uint4 av = *(const uint4*)(eap + k0);
                uint4 wv = *(const uint4*)(ewp + k0);
                __syncthreads();
                *(uint4*)&sA[srow][scol] = av;
                *(uint4*)&sA[64 + srow][scol] = wv;
                __syncthreads();
                bfx8 a = *(const bfx8*)&sA[wave * 16 + r15][kk];
#pragma unroll
                for (int n = 0; n < 4; n++) {
                    bfx8 w = *(const bfx8*)&sA[64 + n * 16 + r15][kk];
                    eacc[n] = MFMA(a, w, eacc[n], 0, 0, 0);
                }
            }
            int rowb = mm0 + wave * 16 + q * 4;
#pragma unroll
            for (int n = 0; n < 4; n++) {
                int c = n0e + n * 16 + r15;
#pragma unroll
                for (int r = 0; r < 4; r++)
                    g_enc_part[((size_t)t * 512 + rowb + r) * 1024 + c] =
                        (__bf16)eacc[n][r];
            }
        }
        grid_sync(0, 256);
        pp ^= 1;
    }
    // hand off h_enc (f32) to decoder
#pragma unroll
    for (int rt = 0; rt < 2; rt++)
#pragma unroll
        for (int reg = 0; reg < 4; reg++) {
            int b_ = m0 + wave * 32 + rt * 16 + q * 4 + reg;
            g_h[(size_t)b_ * 1024 + jj] = hr[rt][reg];
        }
}

// ---------------------------------------------------------------------------
// AD phase: combined [hpart | logits] GEMM on hb. Blocks 0..127: hpart tile;
// 128..143 (lrow>=0): logits tile. Others idle.
// ---------------------------------------------------------------------------
__device__ __forceinline__ void ad_phase(
    int bid, int tid, const __bf16* src, int lrow,
    const float* __restrict__ battn, const float* __restrict__ bout,
    float* __restrict__ outp, __bf16 (*As)[40], __bf16 (*Ws)[40])
{
    const __bf16* W; const float* bias; float* C;
    int ldw, ldc, guard, n0, mm0;
    if (bid < 128) {
        n0 = (bid & 15) * 64; mm0 = (bid >> 4) * 64;
        W = g_WattnT; ldw = 2048; bias = battn;
        C = g_hpart; ldc = 1024; guard = 1024;
    } else if (bid < 144 && lrow >= 0) {
        int t = bid - 128;
        n0 = (t & 1) * 64; mm0 = (t >> 1) * 64;
        W = g_WoutT; ldw = 1024; bias = bout;
        C = outp + (size_t)lrow * 35840; ldc = 70; guard = 70;
    } else return;

    const int wave = tid >> 6, lane = tid & 63;
    const int r15 = lane & 15, q = lane >> 4, kk = q * 8;
    const int srow = tid >> 2, scol = (tid & 3) * 8;
    const __bf16* ap = src + (size_t)(mm0 + srow) * 1024 + scol;
    const __bf16* wp = W + (size_t)(n0 + srow) * ldw + scol;
    f32x4 acc[4];
#pragma unroll
    for (int n = 0; n < 4; n++) acc[n] = (f32x4){0.f, 0.f, 0.f, 0.f};
    for (int k0 = 0; k0 < 1024; k0 += 32) {
        uint4 av = *(const uint4*)(ap + k0);
        uint4 wv = *(const uint4*)(wp + k0);
        __syncthreads();
        *(uint4*)&As[srow][scol] = av;
        *(uint4*)&Ws[srow][scol] = wv;
        __syncthreads();
        bfx8 a = *(const bfx8*)&As[wave * 16 + r15][kk];
#pragma unroll
        for (int n = 0; n < 4; n++) {
            bfx8 w = *(const bfx8*)&Ws[n * 16 + r15][kk];
            acc[n] = MFMA(a, w, acc[n], 0, 0, 0);
        }
    }
    int rowb = mm0 + wave * 16 + q * 4;
#pragma unroll
    for (int n = 0; n < 4; n++) {
        int c = n0 + n * 16 + r15;
        if (c >= guard) continue;
        float bv = bias[c];
#pragma unroll
        for (int r = 0; r < 4; r++)
            C[(size_t)(rowb + r) * ldc + c] = acc[n][r] + bv;
    }
}

// ---------------------------------------------------------------------------
// Persistent decoder. 512 blocks (2/CU). Per step: B (attn, b=bid) -> sync ->
// C (gru, j-tile 64 x m-tile 16) -> sync -> AD (hpart+logits) -> sync.
// ---------------------------------------------------------------------------
__global__ __launch_bounds__(256, 2) void dec_persistent(
    const int* __restrict__ target, const int* __restrict__ tf,
    const float* __restrict__ vattn, const float* __restrict__ battn,
    const float* __restrict__ b1,   // b_hh_dec
    const float* __restrict__ b2,   // b_ih_dec
    const float* __restrict__ bout, float* __restrict__ outp)
{
    __shared__ __bf16 sW3[3][64][40];
    __shared__ __bf16 sA64[64][40];
    __shared__ float sc[32], sal[32];
    __shared__ int sx;
    const int tid = threadIdx.x, bid = blockIdx.x;
    const int wave = tid >> 6, lane = tid & 63;
    const int r15 = lane & 15, q = lane >> 4, kk = q * 8;
    // C-role tile
    const int j0 = (bid & 15) * 64, m0c = (bid >> 4) * 16;
    const int jj = j0 + wave * 16 + r15;
    float hreg[4];
#pragma unroll
    for (int reg = 0; reg < 4; reg++)
        hreg[reg] = g_h[(size_t)(m0c + q * 4 + reg) * 1024 + jj];
    const float cb1[3] = {b1[jj], b1[1024 + jj], b1[2048 + jj]};
    const float cb2[3] = {b2[jj], b2[1024 + jj], b2[2048 + jj]};
    int pp = 0;

    for (int j = -1; j < 31; j++) {
        if (j >= 0) {
            // ================= B: attention for b = bid =================
            const int b = bid;
            if (wave == 0) {
                int xv;
                if (j == 0) xv = target[b];
                else if (*tf) xv = target[j * 512 + b];
                else {
                    const float* row = outp + (size_t)j * 35840 + b * 70;
                    float bv = row[lane]; int bi = lane;
                    if (lane < 6) {
                        float v2 = row[lane + 64];
                        if (v2 > bv) { bv = v2; bi = lane + 64; }
                    }
#pragma unroll
                    for (int off = 32; off; off >>= 1) {
                        float ov = __shfl_down(bv, off);
                        int   oi = __shfl_down(bi, off);
                        if (ov > bv || (ov == bv && oi < bi)) { bv = ov; bi = oi; }
                    }
                    xv = bi;
                }
                if (lane == 0) sx = (xv < 0) ? 0 : (xv > 69 ? 69 : xv);
            }
            float hpv[16], vsv[16];
            {
                const float* hp = g_hpart + (size_t)b * 1024;
#pragma unroll
                for (int u = 0; u < 8; u++) {
                    hpv[u]     = hp[lane * 8 + u];
                    hpv[8 + u] = hp[512 + lane * 8 + u];
                    vsv[u]     = vattn[lane * 8 + u];
                    vsv[8 + u] = vattn[512 + lane * 8 + u];
                }
            }
            __syncthreads();
            g_Adec[(size_t)b * 1280 + 1024 + tid] = g_embt[sx * 256 + tid];
            for (int s = wave * 8; s < wave * 8 + 8; s++) {
                const __bf16* ep = g_enc_part + ((size_t)s * 512 + b) * 1024;
                bfx8 e0 = *(const bfx8*)(ep + lane * 8);
                bfx8 e1 = *(const bfx8*)(ep + 512 + lane * 8);
                float part = 0.f;
#pragma unroll
                for (int u = 0; u < 8; u++) {
                    part += vsv[u]     * fast_tanh((float)e0[u] + hpv[u]);
                    part += vsv[8 + u] * fast_tanh((float)e1[u] + hpv[8 + u]);
                }
#pragma unroll
                for (int off = 32; off; off >>= 1) part += __shfl_down(part, off);
                if (lane == 0) sc[s] = part;
            }
            __syncthreads();
            float mx = sc[0];
#pragma unroll
            for (int s = 1; s < 32; s++) mx = fmaxf(mx, sc[s]);
            float den = 0.f;
#pragma unroll
            for (int s = 0; s < 32; s++) den += __expf(sc[s] - mx);
            float rden = 1.f / den;
            if (tid < 32) {
                float al = __expf(sc[tid] - mx) * rden;
                sal[tid] = al;
                outp[1146880 + (size_t)j * 16384 + b * 32 + tid] = al;
            }
            __syncthreads();
            {
                float c0 = 0, c1 = 0, c2 = 0, c3 = 0;
                const __bf16* eo = g_enc_ops + (size_t)b * 1024 + tid * 4;
#pragma unroll 4
                for (int s = 0; s < 32; s++) {
                    bfx4 e = *(const bfx4*)(eo + (size_t)s * 524288);
                    float al = sal[s];
                    c0 += al * (float)e[0]; c1 += al * (float)e[1];
                    c2 += al * (float)e[2]; c3 += al * (float)e[3];
                }
                bfx4 o = {(__bf16)c0, (__bf16)c1, (__bf16)c2, (__bf16)c3};
                *(bfx4*)(&g_Adec[(size_t)b * 1280 + tid * 4]) = o;
            }
            grid_sync(1, 512);
            // ================= C: GRU step =================
            {
                const __bf16* cur = g_hb[pp];
                __bf16* nxt = g_hb[pp ^ 1];
                f32x4 a1[3], a2[3];
#pragma unroll
                for (int s = 0; s < 3; s++) {
                    a1[s] = (f32x4){0.f, 0.f, 0.f, 0.f};
                    a2[s] = (f32x4){0.f, 0.f, 0.f, 0.f};
                }
                const int war = tid >> 2, wac = (tid & 3) * 8;
                const int aar = tid >> 3, aac = (tid & 7) * 4;
                // phase 1: gh = h @ Whhd^T, K=1024
                {
                    const __bf16* ap = cur + (size_t)(m0c + aar) * 1024 + aac;
                    for (int k0 = 0; k0 < 1024; k0 += 32) {
                        uint2 av;
                        if (tid < 128) av = *(const uint2*)(ap + k0);
                        uint4 w0 = *(const uint4*)&g_Whhd[(size_t)(j0 + war) * 1024 + k0 + wac];
                        uint4 w1 = *(const uint4*)&g_Whhd[(size_t)(1024 + j0 + war) * 1024 + k0 + wac];
                        uint4 w2 = *(const uint4*)&g_Whhd[(size_t)(2048 + j0 + war) * 1024 + k0 + wac];
                        __syncthreads();
                        if (tid < 128) *(uint2*)&sA64[aar][aac] = av;
                        *(uint4*)&sW3[0][war][wac] = w0;
                        *(uint4*)&sW3[1][war][wac] = w1;
                        *(uint4*)&sW3[2][war][wac] = w2;
                        __syncthreads();
                        bfx8 f = *(const bfx8*)&sA64[r15][kk];
#pragma unroll
                        for (int s = 0; s < 3; s++) {
                            bfx8 w = *(const bfx8*)&sW3[s][wave * 16 + r15][kk];
                            a1[s] = MFMA(f, w, a1[s], 0, 0, 0);
                        }
                    }
                }
                // phase 2: gi = [ctx|emb] @ Wihd^T, K=1280
                {
                    const __bf16* ap = g_Adec + (size_t)(m0c + aar) * 1280 + aac;
                    for (int k0 = 0; k0 < 1280; k0 += 32) {
                        uint2 av;
                        if (tid < 128) av = *(const uint2*)(ap + k0);
                        uint4 w0 = *(const uint4*)&g_Wihd[(size_t)(j0 + war) * 1280 + k0 + wac];
                        uint4 w1 = *(const uint4*)&g_Wihd[(size_t)(1024 + j0 + war) * 1280 + k0 + wac];
                        uint4 w2 = *(const uint4*)&g_Wihd[(size_t)(2048 + j0 + war) * 1280 + k0 + wac];
                        __syncthreads();
                        if (tid < 128) *(uint2*)&sA64[aar][aac] = av;
                        *(uint4*)&sW3[0][war][wac] = w0;
                        *(uint4*)&sW3[1][war][wac] = w1;
                        *(uint4*)&sW3[2][war][wac] = w2;
                        __syncthreads();
                        bfx8 f = *(const bfx8*)&sA64[r15][kk];
#pragma unroll
                        for (int s = 0; s < 3; s++) {
                            bfx8 w = *(const bfx8*)&sW3[s][wave * 16 + r15][kk];
                            a2[s] = MFMA(f, w, a2[s], 0, 0, 0);
                        }
                    }
                }
#pragma unroll
                for (int reg = 0; reg < 4; reg++) {
                    int b_ = m0c + q * 4 + reg;
                    float gh0 = a1[0][reg] + cb1[0];
                    float gh1 = a1[1][reg] + cb1[1];
                    float gh2 = a1[2][reg] + cb1[2];
                    float gi0 = a2[0][reg] + cb2[0];
                    float gi1 = a2[1][reg] + cb2[1];
                    float gi2 = a2[2][reg] + cb2[2];
                    float r = 1.f / (1.f + __expf(-(gi0 + gh0)));
                    float z = 1.f / (1.f + __expf(-(gi1 + gh1)));
                    float n = fast_tanh(gi2 + r * gh2);
                    float hv = (1.f - z) * n + z * hreg[reg];
                    hreg[reg] = hv;
                    nxt[(size_t)b_ * 1024 + jj] = (__bf16)hv;
                }
            }
            grid_sync(1, 512);
        }
        // ================= AD: [hpart | logits] =================
        const __bf16* adsrc = (j >= 0) ? g_hb[pp ^ 1] : g_hb[0];
        ad_phase(bid, tid, adsrc, (j >= 0) ? j + 1 : -1, battn, bout, outp,
                 sA64, sW3[0]);
        grid_sync(1, 512);
        if (j >= 0) pp ^= 1;
    }
}

// ---------------------------------------------------------------------------
extern "C" void kernel_launch(void* const* d_in, const int* in_sizes, int n_in,
                              void* d_out, int out_size, void* d_ws, size_t ws_size,
                              hipStream_t stream)
{
    const int*   source   = (const int*)d_in[0];
    const int*   target   = (const int*)d_in[1];
    const int*   tf       = (const int*)d_in[2];
    const float* emb_src  = (const float*)d_in[3];
    const float* W_ih_enc = (const float*)d_in[4];
    const float* W_hh_enc = (const float*)d_in[5];
    const float* b_ih_enc = (const float*)d_in[6];
    const float* b_hh_enc = (const float*)d_in[7];
    const float* emb_tgt  = (const float*)d_in[8];
    const float* W_attn   = (const float*)d_in[9];
    const float* b_attn   = (const float*)d_in[10];
    const float* v_attn   = (const float*)d_in[11];
    const float* W_ih_dec = (const float*)d_in[12];
    const float* W_hh_dec = (const float*)d_in[13];
    const float* b_ih_dec = (const float*)d_in[14];
    const float* b_hh_dec = (const float*)d_in[15];
    const float* W_out    = (const float*)d_in[16];
    const float* b_out    = (const float*)d_in[17];
    float* out = (float*)d_out;

    void *p_Whhe, *p_Wihe, *p_Whhd, *p_Wihd, *p_embs, *p_embt;
    hipGetSymbolAddress(&p_Whhe, HIP_SYMBOL(g_Whhe));
    hipGetSymbolAddress(&p_Wihe, HIP_SYMBOL(g_Wihe));
    hipGetSymbolAddress(&p_Whhd, HIP_SYMBOL(g_Whhd));
    hipGetSymbolAddress(&p_Wihd, HIP_SYMBOL(g_Wihd));
    hipGetSymbolAddress(&p_embs, HIP_SYMBOL(g_embs));
    hipGetSymbolAddress(&p_embt, HIP_SYMBOL(g_embt));

    auto cvt = [&](const float* s, void* d, int n) {
        k_cvt<<<(n / 4 + 255) / 256, 256, 0, stream>>>(s, (__bf16*)d, n / 4);
    };
    cvt(W_hh_enc, p_Whhe, 3072 * 1024);
    cvt(W_ih_enc, p_Wihe, 3072 * 256);
    cvt(W_hh_dec, p_Whhd, 3072 * 1024);
    cvt(W_ih_dec, p_Wihd, 3072 * 1280);
    cvt(emb_src,  p_embs, 64 * 256);
    cvt(emb_tgt,  p_embt, 70 * 256);
    k_transpose<<<dim3(32, 64), 256, 0, stream>>>(W_attn);
    k_cvtWout<<<512, 256, 0, stream>>>(W_out);
    k_init<<<2048, 256, 0, stream>>>(out);

    enc_persistent<<<256, 256, 0, stream>>>(source, b_hh_enc, b_ih_enc);
    dec_persistent<<<512, 256, 0, stream>>>(target, tf, v_attn, b_attn,
                                            b_hh_dec, b_ih_dec, b_out, out);
}

// Round 6
// 5107.880 us; speedup vs baseline: 3.2936x; 3.2936x over previous
//
#include <hip/hip_runtime.h>
#include <hip/hip_bf16.h>

typedef __bf16 bfx8 __attribute__((ext_vector_type(8)));
typedef __bf16 bfx4 __attribute__((ext_vector_type(4)));
typedef float f32x4 __attribute__((ext_vector_type(4)));

#define MFMA __builtin_amdgcn_mfma_f32_16x16x32_bf16

// Dims: S=32 T=32 B=512 H=1024 E=256 A=1024 VS=64 VT=70 START=1
// Float tensors f32 in/out; MFMA on bf16 copies; h master kept f32.
// All MFMA operands loaded DIRECTLY global->VGPR (A and W are both row-major
// in K, matching the 16x16x32 fragment layout). No LDS, no __syncthreads in
// any hot K-loop -> compiler software-pipelines; 2 blocks/CU hide latency.

__device__ __attribute__((aligned(256))) float  g_h[512 * 1024];
__device__ __attribute__((aligned(256))) float  g_hpart[512 * 1024];
__device__ __attribute__((aligned(256))) __bf16 g_hb[2][512 * 1024];
__device__ __attribute__((aligned(256))) __bf16 g_Adec[512 * 1280];
__device__ __attribute__((aligned(256))) __bf16 g_enc_ops[(size_t)32 * 512 * 1024];
__device__ __attribute__((aligned(256))) __bf16 g_enc_part[(size_t)32 * 512 * 1024];
__device__ __attribute__((aligned(256))) __bf16 g_WattnT[(size_t)1024 * 2048];
__device__ __attribute__((aligned(256))) __bf16 g_Whhe[3072 * 1024];
__device__ __attribute__((aligned(256))) __bf16 g_Wihe[3072 * 256];
__device__ __attribute__((aligned(256))) __bf16 g_Whhd[3072 * 1024];
__device__ __attribute__((aligned(256))) __bf16 g_Wihd[3072 * 1280];
__device__ __attribute__((aligned(256))) __bf16 g_WoutT[128 * 1024];
__device__ __attribute__((aligned(256))) __bf16 g_embs[64 * 256];
__device__ __attribute__((aligned(256))) __bf16 g_embt[70 * 256];

__device__ __forceinline__ float fast_tanh(float x) {
    float cx = fminf(fmaxf(x, -15.f), 15.f);
    float e = __expf(-2.f * cx);
    return (1.f - e) / (1.f + e);
}

// ---------------------------------------------------------------------------
__global__ void k_cvt(const float* __restrict__ src, __bf16* __restrict__ dst,
                      int n4)
{
    int i = blockIdx.x * 256 + threadIdx.x;
    if (i >= n4) return;
    float4 v = ((const float4*)src)[i];
    __bf16 o[4] = {(__bf16)v.x, (__bf16)v.y, (__bf16)v.z, (__bf16)v.w};
    *(ushort2*)(dst + 4 * i) = *(ushort2*)o;
    *(ushort2*)(dst + 4 * i + 2) = *(ushort2*)(o + 2);
}

__global__ __launch_bounds__(256) void k_transpose(const float* __restrict__ Wsrc)
{
    __shared__ float t[32][33];
    int bx = blockIdx.x, by = blockIdx.y;
    int lx = threadIdx.x & 31, ly = threadIdx.x >> 5;
    for (int i = 0; i < 32; i += 8)
        t[ly + i][lx] = Wsrc[(size_t)(by * 32 + ly + i) * 1024 + bx * 32 + lx];
    __syncthreads();
    for (int i = 0; i < 32; i += 8)
        g_WattnT[(size_t)(bx * 32 + ly + i) * 2048 + by * 32 + lx] =
            (__bf16)t[lx][ly + i];
}

__global__ void k_cvtWout(const float* __restrict__ W)
{
    int idx = blockIdx.x * 256 + threadIdx.x;  // < 128*1024
    int c = idx >> 10, k = idx & 1023;
    g_WoutT[idx] = (__bf16)((c < 70) ? W[k * 70 + c] : 0.f);
}

__global__ void k_init(float* __restrict__ out)
{
    int idx = blockIdx.x * 256 + threadIdx.x;
    if (idx < 512 * 1024) { g_h[idx] = 0.f; g_hb[0][idx] = (__bf16)0.f; }
    if (idx < 512 * 70) out[idx] = (idx % 70 == 1) ? 1.f : 0.f;
}

// ---------------------------------------------------------------------------
// Fused GRU step, barrier-free. grid (16 j-tiles, 32 m-tiles) = 512 blocks.
// Block: 16 batch rows x 64 j x 3 gate slabs. Wave w: j-subtile j0+16w.
// gh = hb_in @ W1^T (K=1024);  gi = A2 @ W2^T (K2), opt row-gather.
// Epilogue: GRU combine; writes g_h, hb_out, optionally enc_ops[enc_t].
// ---------------------------------------------------------------------------
__global__ __launch_bounds__(256) void gru_step(
    const __bf16* __restrict__ hb_in, __bf16* __restrict__ hb_out,
    const __bf16* __restrict__ W1, const float* __restrict__ b1,
    const __bf16* __restrict__ A2, int lda2,
    const int* __restrict__ arows2, int amax2,
    const __bf16* __restrict__ W2, int ldw2, const float* __restrict__ b2,
    int K2, int enc_t)
{
    const int tid = threadIdx.x;
    const int wave = tid >> 6, lane = tid & 63;
    const int r15 = lane & 15, q = lane >> 4;
    const int j0 = blockIdx.x * 64;
    const int m0 = blockIdx.y * 16;
    const int jw = j0 + wave * 16;

    f32x4 acc1[3], acc2[3];
#pragma unroll
    for (int s = 0; s < 3; s++) {
        acc1[s] = (f32x4){0.f, 0.f, 0.f, 0.f};
        acc2[s] = (f32x4){0.f, 0.f, 0.f, 0.f};
    }

    // ---- phase 1: gh = hb_in @ W1^T, K=1024 ----
    {
        const __bf16* ap  = hb_in + (size_t)(m0 + r15) * 1024 + q * 8;
        const __bf16* wp0 = W1 + (size_t)(jw + r15) * 1024 + q * 8;
        const __bf16* wp1 = wp0 + (size_t)1024 * 1024;
        const __bf16* wp2 = wp1 + (size_t)1024 * 1024;
#pragma unroll 4
        for (int k0 = 0; k0 < 1024; k0 += 32) {
            bfx8 a  = *(const bfx8*)(ap + k0);
            bfx8 w0 = *(const bfx8*)(wp0 + k0);
            bfx8 w1 = *(const bfx8*)(wp1 + k0);
            bfx8 w2 = *(const bfx8*)(wp2 + k0);
            acc1[0] = MFMA(a, w0, acc1[0], 0, 0, 0);
            acc1[1] = MFMA(a, w1, acc1[1], 0, 0, 0);
            acc1[2] = MFMA(a, w2, acc1[2], 0, 0, 0);
        }
    }
    // ---- phase 2: gi = A2 @ W2^T, K=K2 ----
    {
        size_t arow = m0 + r15;
        if (arows2) {
            int v = arows2[arow];
            arow = (size_t)((v < 0) ? 0 : (v > amax2 ? amax2 : v));
        }
        const __bf16* ap  = A2 + arow * (size_t)lda2 + q * 8;
        const __bf16* wp0 = W2 + (size_t)(jw + r15) * ldw2 + q * 8;
        const __bf16* wp1 = wp0 + (size_t)1024 * ldw2;
        const __bf16* wp2 = wp1 + (size_t)1024 * ldw2;
#pragma unroll 4
        for (int k0 = 0; k0 < K2; k0 += 32) {
            bfx8 a  = *(const bfx8*)(ap + k0);
            bfx8 w0 = *(const bfx8*)(wp0 + k0);
            bfx8 w1 = *(const bfx8*)(wp1 + k0);
            bfx8 w2 = *(const bfx8*)(wp2 + k0);
            acc2[0] = MFMA(a, w0, acc2[0], 0, 0, 0);
            acc2[1] = MFMA(a, w1, acc2[1], 0, 0, 0);
            acc2[2] = MFMA(a, w2, acc2[2], 0, 0, 0);
        }
    }
    // ---- GRU epilogue ----
    const int jj = jw + r15;
    const float bb1[3] = {b1[jj], b1[1024 + jj], b1[2048 + jj]};
    const float bb2[3] = {b2[jj], b2[1024 + jj], b2[2048 + jj]};
#pragma unroll
    for (int reg = 0; reg < 4; reg++) {
        int b_ = m0 + q * 4 + reg;
        float gh0 = acc1[0][reg] + bb1[0];
        float gh1 = acc1[1][reg] + bb1[1];
        float gh2 = acc1[2][reg] + bb1[2];
        float gi0 = acc2[0][reg] + bb2[0];
        float gi1 = acc2[1][reg] + bb2[1];
        float gi2 = acc2[2][reg] + bb2[2];
        float r = 1.f / (1.f + __expf(-(gi0 + gh0)));
        float z = 1.f / (1.f + __expf(-(gi1 + gh1)));
        float n = fast_tanh(gi2 + r * gh2);
        size_t off = (size_t)b_ * 1024 + jj;
        float hv = (1.f - z) * n + z * g_h[off];
        g_h[off] = hv;
        hb_out[off] = (__bf16)hv;
        if (enc_t >= 0) g_enc_ops[(size_t)enc_t * 524288 + off] = (__bf16)hv;
    }
}

// ---------------------------------------------------------------------------
// Fused [hpart | logits] GEMM from current h (bf16). grid (18, 32).
// bx<16: hpart tile (N=1024, +b_attn). bx>=16 (lrow>=0): logits tile
// (N=128 guard 70, +b_out) -> out row lrow. Barrier-free, no LDS.
// ---------------------------------------------------------------------------
__global__ __launch_bounds__(256) void k_hl(
    const __bf16* __restrict__ src, const float* __restrict__ battn,
    const float* __restrict__ bout, int lrow, float* __restrict__ outp)
{
    const int tid = threadIdx.x;
    const int wave = tid >> 6, lane = tid & 63;
    const int r15 = lane & 15, q = lane >> 4;
    const int bx = blockIdx.x, m0 = blockIdx.y * 16;

    const __bf16* W; const float* bias; float* C;
    int ldw, ldc, guard, n0;
    if (bx < 16) {
        W = g_WattnT; ldw = 2048; bias = battn;
        C = g_hpart;  ldc = 1024; guard = 1024; n0 = bx * 64;
    } else {
        if (lrow < 0) return;
        W = g_WoutT; ldw = 1024; bias = bout;
        C = outp + (size_t)lrow * 35840; ldc = 70; guard = 70;
        n0 = (bx - 16) * 64;
    }
    const int nw = n0 + wave * 16;

    f32x4 acc = (f32x4){0.f, 0.f, 0.f, 0.f};
    const __bf16* ap = src + (size_t)(m0 + r15) * 1024 + q * 8;
    const __bf16* wp = W + (size_t)(nw + r15) * ldw + q * 8;
#pragma unroll 4
    for (int k0 = 0; k0 < 1024; k0 += 32) {
        bfx8 a = *(const bfx8*)(ap + k0);
        bfx8 w = *(const bfx8*)(wp + k0);
        acc = MFMA(a, w, acc, 0, 0, 0);
    }
    int c = nw + r15;
    if (c >= guard) return;
    float bv = bias[c];
#pragma unroll
    for (int reg = 0; reg < 4; reg++) {
        int b_ = m0 + q * 4 + reg;
        C[(size_t)b_ * ldc + c] = acc[reg] + bv;
    }
}

// ---------------------------------------------------------------------------
// enc_part = enc_ops @ W_attn[H:2H]^T  (M=16384, N=1024, K=1024), bf16 out.
// grid (16, 256): block 64m x 64n; wave w: m-subtile w*16, all 64 n.
// ---------------------------------------------------------------------------
__global__ __launch_bounds__(256) void gemm_ep()
{
    const int tid = threadIdx.x;
    const int wave = tid >> 6, lane = tid & 63;
    const int r15 = lane & 15, q = lane >> 4;
    const int n0 = blockIdx.x * 64;
    const int m0 = blockIdx.y * 64 + wave * 16;

    f32x4 acc[4];
#pragma unroll
    for (int n = 0; n < 4; n++) acc[n] = (f32x4){0.f, 0.f, 0.f, 0.f};

    const __bf16* ap = g_enc_ops + (size_t)(m0 + r15) * 1024 + q * 8;
    const __bf16* wp0 = g_WattnT + (size_t)(n0 + r15) * 2048 + 1024 + q * 8;
#pragma unroll 2
    for (int k0 = 0; k0 < 1024; k0 += 32) {
        bfx8 a = *(const bfx8*)(ap + k0);
        bfx8 w0 = *(const bfx8*)(wp0 + k0);
        bfx8 w1 = *(const bfx8*)(wp0 + 16 * 2048 + k0);
        bfx8 w2 = *(const bfx8*)(wp0 + 32 * 2048 + k0);
        bfx8 w3 = *(const bfx8*)(wp0 + 48 * 2048 + k0);
        acc[0] = MFMA(a, w0, acc[0], 0, 0, 0);
        acc[1] = MFMA(a, w1, acc[1], 0, 0, 0);
        acc[2] = MFMA(a, w2, acc[2], 0, 0, 0);
        acc[3] = MFMA(a, w3, acc[3], 0, 0, 0);
    }
#pragma unroll
    for (int n = 0; n < 4; n++) {
        int c = n0 + n * 16 + r15;
#pragma unroll
        for (int reg = 0; reg < 4; reg++) {
            int row = m0 + q * 4 + reg;
            g_enc_part[(size_t)row * 1024 + c] = (__bf16)acc[n][reg];
        }
    }
}

// ---------------------------------------------------------------------------
// Attention step: x-select + embed + scores + softmax + alpha out + ctx.
// One block per batch b.
// ---------------------------------------------------------------------------
__global__ __launch_bounds__(256) void k_attn(
    int j, const int* __restrict__ target, const int* __restrict__ tf,
    const float* __restrict__ v_attn, float* __restrict__ out)
{
    const int b = blockIdx.x, tid = threadIdx.x;
    const int lane = tid & 63, wave = tid >> 6;
    __shared__ float sc[32], sal[32];
    __shared__ int sx;
    if (wave == 0) {
        int xv;
        if (j == 0) xv = target[b];
        else if (*tf) xv = target[j * 512 + b];
        else {
            const float* row = out + (size_t)j * 35840 + b * 70;
            float bv = row[lane]; int bi = lane;
            if (lane < 6) {
                float v2 = row[lane + 64];
                if (v2 > bv) { bv = v2; bi = lane + 64; }
            }
#pragma unroll
            for (int off = 32; off; off >>= 1) {
                float ov = __shfl_down(bv, off);
                int   oi = __shfl_down(bi, off);
                if (ov > bv || (ov == bv && oi < bi)) { bv = ov; bi = oi; }
            }
            xv = bi;
        }
        if (lane == 0) sx = (xv < 0) ? 0 : (xv > 69 ? 69 : xv);
    }
    float hpv[16], vsv[16];
    {
        const float* hp = g_hpart + (size_t)b * 1024;
#pragma unroll
        for (int u = 0; u < 8; u++) {
            hpv[u]     = hp[lane * 8 + u];
            hpv[8 + u] = hp[512 + lane * 8 + u];
            vsv[u]     = v_attn[lane * 8 + u];
            vsv[8 + u] = v_attn[512 + lane * 8 + u];
        }
    }
    __syncthreads();
    g_Adec[(size_t)b * 1280 + 1024 + tid] = g_embt[sx * 256 + tid];
    for (int s = wave * 8; s < wave * 8 + 8; s++) {
        const __bf16* ep = g_enc_part + ((size_t)s * 512 + b) * 1024;
        bfx8 e0 = *(const bfx8*)(ep + lane * 8);
        bfx8 e1 = *(const bfx8*)(ep + 512 + lane * 8);
        float part = 0.f;
#pragma unroll
        for (int u = 0; u < 8; u++) {
            part += vsv[u]     * fast_tanh((float)e0[u] + hpv[u]);
            part += vsv[8 + u] * fast_tanh((float)e1[u] + hpv[8 + u]);
        }
#pragma unroll
        for (int off = 32; off; off >>= 1) part += __shfl_down(part, off);
        if (lane == 0) sc[s] = part;
    }
    __syncthreads();
    float mx = sc[0];
#pragma unroll
    for (int s = 1; s < 32; s++) mx = fmaxf(mx, sc[s]);
    float den = 0.f;
#pragma unroll
    for (int s = 0; s < 32; s++) den += __expf(sc[s] - mx);
    float rden = 1.f / den;
    if (tid < 32) {
        float al = __expf(sc[tid] - mx) * rden;
        sal[tid] = al;
        out[1146880 + (size_t)j * 16384 + b * 32 + tid] = al;
    }
    __syncthreads();
    float c0 = 0, c1 = 0, c2 = 0, c3 = 0;
    const __bf16* eo = g_enc_ops + (size_t)b * 1024 + tid * 4;
#pragma unroll 4
    for (int s = 0; s < 32; s++) {
        bfx4 e = *(const bfx4*)(eo + (size_t)s * 524288);
        float al = sal[s];
        c0 += al * (float)e[0]; c1 += al * (float)e[1];
        c2 += al * (float)e[2]; c3 += al * (float)e[3];
    }
    bfx4 o = {(__bf16)c0, (__bf16)c1, (__bf16)c2, (__bf16)c3};
    *(bfx4*)(&g_Adec[(size_t)b * 1280 + tid * 4]) = o;
}

// ---------------------------------------------------------------------------
extern "C" void kernel_launch(void* const* d_in, const int* in_sizes, int n_in,
                              void* d_out, int out_size, void* d_ws, size_t ws_size,
                              hipStream_t stream)
{
    const int*   source   = (const int*)d_in[0];
    const int*   target   = (const int*)d_in[1];
    const int*   tf       = (const int*)d_in[2];
    const float* emb_src  = (const float*)d_in[3];
    const float* W_ih_enc = (const float*)d_in[4];
    const float* W_hh_enc = (const float*)d_in[5];
    const float* b_ih_enc = (const float*)d_in[6];
    const float* b_hh_enc = (const float*)d_in[7];
    const float* emb_tgt  = (const float*)d_in[8];
    const float* W_attn   = (const float*)d_in[9];
    const float* b_attn   = (const float*)d_in[10];
    const float* v_attn   = (const float*)d_in[11];
    const float* W_ih_dec = (const float*)d_in[12];
    const float* W_hh_dec = (const float*)d_in[13];
    const float* b_ih_dec = (const float*)d_in[14];
    const float* b_hh_dec = (const float*)d_in[15];
    const float* W_out    = (const float*)d_in[16];
    const float* b_out    = (const float*)d_in[17];
    float* out = (float*)d_out;

    void *p_hb, *p_Whhe, *p_Wihe, *p_Whhd, *p_Wihd, *p_embs, *p_embt;
    hipGetSymbolAddress(&p_hb,   HIP_SYMBOL(g_hb));
    hipGetSymbolAddress(&p_Whhe, HIP_SYMBOL(g_Whhe));
    hipGetSymbolAddress(&p_Wihe, HIP_SYMBOL(g_Wihe));
    hipGetSymbolAddress(&p_Whhd, HIP_SYMBOL(g_Whhd));
    hipGetSymbolAddress(&p_Wihd, HIP_SYMBOL(g_Wihd));
    hipGetSymbolAddress(&p_embs, HIP_SYMBOL(g_embs));
    hipGetSymbolAddress(&p_embt, HIP_SYMBOL(g_embt));
    __bf16* hb0 = (__bf16*)p_hb;
    __bf16* hb1 = hb0 + 512 * 1024;
    __bf16* Adec;
    {
        void* p; hipGetSymbolAddress(&p, HIP_SYMBOL(g_Adec));
        Adec = (__bf16*)p;
    }

    auto cvt = [&](const float* s, void* d, int n) {
        k_cvt<<<(n / 4 + 255) / 256, 256, 0, stream>>>(s, (__bf16*)d, n / 4);
    };
    cvt(W_hh_enc, p_Whhe, 3072 * 1024);
    cvt(W_ih_enc, p_Wihe, 3072 * 256);
    cvt(W_hh_dec, p_Whhd, 3072 * 1024);
    cvt(W_ih_dec, p_Wihd, 3072 * 1280);
    cvt(emb_src,  p_embs, 64 * 256);
    cvt(emb_tgt,  p_embt, 70 * 256);
    k_transpose<<<dim3(32, 64), 256, 0, stream>>>(W_attn);
    k_cvtWout<<<512, 256, 0, stream>>>(W_out);
    k_init<<<2048, 256, 0, stream>>>(out);

    // -------- Encoder: 32 fused barrier-free steps --------
    for (int t = 0; t < 32; t++) {
        __bf16* hin  = (t & 1) ? hb1 : hb0;
        __bf16* hout = (t & 1) ? hb0 : hb1;
        gru_step<<<dim3(16, 32), 256, 0, stream>>>(
            hin, hout, (__bf16*)p_Whhe, b_hh_enc,
            (__bf16*)p_embs, 256, source + t * 512, 63,
            (__bf16*)p_Wihe, 256, b_ih_enc, 256, t);
    }
    // h_enc lands in hb0

    gemm_ep<<<dim3(16, 256), 256, 0, stream>>>();

    // hpart for step 0 (no logits)
    k_hl<<<dim3(18, 32), 256, 0, stream>>>(hb0, b_attn, b_out, -1, out);

    // -------- Decoder: 31 steps, 3 dispatches each --------
    for (int j = 0; j < 31; j++) {
        __bf16* hin  = (j & 1) ? hb1 : hb0;
        __bf16* hout = (j & 1) ? hb0 : hb1;
        k_attn<<<512, 256, 0, stream>>>(j, target, tf, v_attn, out);
        gru_step<<<dim3(16, 32), 256, 0, stream>>>(
            hin, hout, (__bf16*)p_Whhd, b_hh_dec,
            Adec, 1280, nullptr, 0,
            (__bf16*)p_Wihd, 1280, b_ih_dec, 1280, -1);
        // hpart for step j+1 + logits row j+1
        k_hl<<<dim3(18, 32), 256, 0, stream>>>(hout, b_attn, b_out, j + 1, out);
    }
}

// Round 7
// 2670.408 us; speedup vs baseline: 6.3000x; 1.9128x over previous
//
#include <hip/hip_runtime.h>
#include <hip/hip_bf16.h>

typedef __bf16 bfx8 __attribute__((ext_vector_type(8)));
typedef __bf16 bfx4 __attribute__((ext_vector_type(4)));
typedef float f32x4 __attribute__((ext_vector_type(4)));

#define MFMA __builtin_amdgcn_mfma_f32_16x16x32_bf16

// Dims: S=32 T=32 B=512 H=1024 E=256 A=1024 VS=64 VT=70 START=1
// f32 in/out; MFMA on bf16. Weights pre-swizzled to FRAGMENT-MAJOR layout:
// fragment (t=row/16, c=k/32) stored as 64 lanes x 16B contiguous -> coalesced
// 1KB wave loads, no LDS for W. A-tiles staged once into XOR-swizzled LDS
// (conflict-free ds_read_b128), K-loops barrier-free.

__device__ __attribute__((aligned(256))) float  g_h[512 * 1024];
__device__ __attribute__((aligned(256))) float  g_hpart[512 * 1024];
__device__ __attribute__((aligned(256))) __bf16 g_hb[2][512 * 1024];
__device__ __attribute__((aligned(256))) __bf16 g_Adec[512 * 1280];
__device__ __attribute__((aligned(256))) __bf16 g_enc_ops[(size_t)32 * 512 * 1024];
__device__ __attribute__((aligned(256))) __bf16 g_enc_part[(size_t)32 * 512 * 1024];
__device__ __attribute__((aligned(256))) __bf16 g_WattnT[(size_t)1024 * 2048];  // row-major [a][f], for gemm_ep
__device__ __attribute__((aligned(256))) __bf16 g_sWhhe[(size_t)3072 * 1024];   // swizzled
__device__ __attribute__((aligned(256))) __bf16 g_sWihe[(size_t)3072 * 256];
__device__ __attribute__((aligned(256))) __bf16 g_sWhhd[(size_t)3072 * 1024];
__device__ __attribute__((aligned(256))) __bf16 g_sWihd[(size_t)3072 * 1280];
__device__ __attribute__((aligned(256))) __bf16 g_sWattnA[(size_t)1024 * 1024];
__device__ __attribute__((aligned(256))) __bf16 g_sWout[(size_t)128 * 1024];
__device__ __attribute__((aligned(256))) __bf16 g_embs[64 * 256];
__device__ __attribute__((aligned(256))) __bf16 g_embt[70 * 256];

__device__ __forceinline__ float fast_tanh(float x) {
    float cx = fminf(fmaxf(x, -15.f), 15.f);
    float e = __expf(-2.f * cx);
    return (1.f - e) / (1.f + e);
}

// ---------------------------------------------------------------------------
__global__ void k_cvt(const float* __restrict__ src, __bf16* __restrict__ dst,
                      int n4)
{
    int i = blockIdx.x * 256 + threadIdx.x;
    if (i >= n4) return;
    float4 v = ((const float4*)src)[i];
    __bf16 o[4] = {(__bf16)v.x, (__bf16)v.y, (__bf16)v.z, (__bf16)v.w};
    *(ushort2*)(dst + 4 * i) = *(ushort2*)o;
    *(ushort2*)(dst + 4 * i + 2) = *(ushort2*)(o + 2);
}

// Swizzle row-major f32 W[R][K] -> fragment-major bf16.
// out[((t*nK+c)*64 + L)*8 + u] = W[t*16 + (L&15)][c*32 + (L>>4)*8 + u]
__global__ void swz_rm(const float* __restrict__ W, __bf16* __restrict__ out,
                       int nK, int total)
{
    int gid = blockIdx.x * 256 + threadIdx.x;
    if (gid >= total) return;
    int F = gid >> 6, L = gid & 63;
    int t = F / nK, c = F - t * nK;
    int K = nK * 32;
    const float* s = W + (size_t)(t * 16 + (L & 15)) * K + c * 32 + (L >> 4) * 8;
    __bf16 o[8];
#pragma unroll
    for (int u = 0; u < 8; u++) o[u] = (__bf16)s[u];
    *(uint4*)(out + (size_t)gid * 8) = *(uint4*)o;
}

// Swizzle column-gather: logical W'[n][k] = W[k*ldsrc + n], n>=nguard -> 0.
__global__ void swz_cm(const float* __restrict__ W, __bf16* __restrict__ out,
                       int nK, int ldsrc, int nguard, int total)
{
    int gid = blockIdx.x * 256 + threadIdx.x;
    if (gid >= total) return;
    int F = gid >> 6, L = gid & 63;
    int t = F / nK, c = F - t * nK;
    int n = t * 16 + (L & 15);
    int k = c * 32 + (L >> 4) * 8;
    __bf16 o[8];
#pragma unroll
    for (int u = 0; u < 8; u++)
        o[u] = (n < nguard) ? (__bf16)W[(size_t)(k + u) * ldsrc + n] : (__bf16)0.f;
    *(uint4*)(out + (size_t)gid * 8) = *(uint4*)o;
}

// W_attn f32 (2048,1024) -> g_WattnT bf16 (1024,2048) row-major (for gemm_ep)
__global__ __launch_bounds__(256) void k_transpose(const float* __restrict__ Wsrc)
{
    __shared__ float t[32][33];
    int bx = blockIdx.x, by = blockIdx.y;
    int lx = threadIdx.x & 31, ly = threadIdx.x >> 5;
    for (int i = 0; i < 32; i += 8)
        t[ly + i][lx] = Wsrc[(size_t)(by * 32 + ly + i) * 1024 + bx * 32 + lx];
    __syncthreads();
    for (int i = 0; i < 32; i += 8)
        g_WattnT[(size_t)(bx * 32 + ly + i) * 2048 + by * 32 + lx] =
            (__bf16)t[lx][ly + i];
}

__global__ void k_init(float* __restrict__ out)
{
    int idx = blockIdx.x * 256 + threadIdx.x;
    if (idx < 512 * 1024) { g_h[idx] = 0.f; g_hb[0][idx] = (__bf16)0.f; }
    if (idx < 512 * 70) out[idx] = (idx % 70 == 1) ? 1.f : 0.f;
}

// ---------------------------------------------------------------------------
// gemm_bt (round-4 LDS version) -- used only for the one-shot enc_part GEMM.
// ---------------------------------------------------------------------------
__global__ __launch_bounds__(256) void gemm_bt(
    const __bf16* __restrict__ Amat, int lda,
    const __bf16* __restrict__ Wmat, int ldw,
    const float* __restrict__ bias,
    void* __restrict__ Cout, int ldc, int cmode, int K, int nguard)
{
    __shared__ __bf16 As[64][40];
    __shared__ __bf16 Ws[64][40];
    const int tid  = threadIdx.x;
    const int m0   = blockIdx.y * 64;
    const int n0   = blockIdx.x * 64;
    const int wave = tid >> 6;
    const int lane = tid & 63;
    const int srow = tid >> 2;
    const int scol = (tid & 3) << 3;

    const __bf16* aptr = Amat + (size_t)(m0 + srow) * lda + scol;
    const __bf16* wptr = Wmat + (size_t)(n0 + srow) * ldw + scol;

    f32x4 acc[4];
#pragma unroll
    for (int i = 0; i < 4; i++) acc[i] = (f32x4){0.f, 0.f, 0.f, 0.f};

    const int r15 = lane & 15;
    const int kk  = (lane >> 4) << 3;

    for (int k0 = 0; k0 < K; k0 += 32) {
        uint4 av = *(const uint4*)(aptr + k0);
        uint4 wv = *(const uint4*)(wptr + k0);
        __syncthreads();
        *(uint4*)(&As[srow][scol]) = av;
        *(uint4*)(&Ws[srow][scol]) = wv;
        __syncthreads();
        bfx8 a = *(const bfx8*)(&As[wave * 16 + r15][kk]);
#pragma unroll
        for (int n = 0; n < 4; n++) {
            bfx8 b = *(const bfx8*)(&Ws[n * 16 + r15][kk]);
            acc[n] = MFMA(a, b, acc[n], 0, 0, 0);
        }
    }

    const int rowb = m0 + wave * 16 + (lane >> 4) * 4;
#pragma unroll
    for (int n = 0; n < 4; n++) {
        int c = n0 + n * 16 + r15;
        if (c >= nguard) continue;
        float bv = bias ? bias[c] : 0.f;
#pragma unroll
        for (int r = 0; r < 4; r++) {
            float v = acc[n][r] + bv;
            size_t off = (size_t)(rowb + r) * ldc + c;
            if (cmode == 0) ((float*)Cout)[off] = v;
            else            ((__bf16*)Cout)[off] = (__bf16)v;
        }
    }
}

// ---------------------------------------------------------------------------
// Fused GRU step v2. grid (16 j-tiles, 16 m-tiles) = 256 blocks, 4 waves.
// Block: 32 batch rows x 64 j x 3 gates. Wave w: j-sub w*16, 2 m-subs, 3 gates.
// A1 (hb 32x1024) + A2 (Adec 32x1280 or emb-gather 32x256) staged once into
// XOR-swizzled LDS; W fragment-major coalesced global loads; no barriers in
// the K-loops.
// ---------------------------------------------------------------------------
__global__ __launch_bounds__(256) void gru_step(
    const __bf16* __restrict__ hb_in, __bf16* __restrict__ hb_out,
    const __bf16* __restrict__ sW1, const float* __restrict__ b1,
    const __bf16* __restrict__ sW2, const float* __restrict__ b2,
    int nK2, const int* __restrict__ src_t, int enc_t)
{
    __shared__ __bf16 sA1[32 * 1024];   // 64 KB
    __shared__ __bf16 sA2[32 * 1280];   // 80 KB
    const int tid = threadIdx.x;
    const int w = tid >> 6, lane = tid & 63;
    const int r15 = lane & 15, q = lane >> 4;
    const int j0 = blockIdx.x * 64, m0 = blockIdx.y * 32;

    // ---- stage A1: 32 rows x 128 16B-units, xor-swizzled ----
#pragma unroll
    for (int i = 0; i < 16; i++) {
        int lin = tid + i * 256;
        int r = lin >> 7, U = lin & 127;
        uint4 v = *(const uint4*)(hb_in + (size_t)(m0 + r) * 1024 + U * 8);
        *(uint4*)(sA1 + (r * 128 + (U ^ (r & 7))) * 8) = v;
    }
    // ---- stage A2 ----
    if (src_t) {  // encoder: gather emb rows, 32 x 32 units
#pragma unroll
        for (int i = 0; i < 4; i++) {
            int lin = tid + i * 256;
            int r = lin >> 5, U = lin & 31;
            int sv = src_t[m0 + r];
            sv = (sv < 0) ? 0 : (sv > 63 ? 63 : sv);
            uint4 v = *(const uint4*)(g_embs + sv * 256 + U * 8);
            *(uint4*)(sA2 + (r * 32 + (U ^ (r & 7))) * 8) = v;
        }
    } else {      // decoder: Adec, 32 x 160 units
        for (int lin = tid; lin < 32 * 160; lin += 256) {
            int r = lin / 160, U = lin - r * 160;
            uint4 v = *(const uint4*)(g_Adec + (size_t)(m0 + r) * 1280 + U * 8);
            *(uint4*)(sA2 + (r * 160 + (U ^ (r & 7))) * 8) = v;
        }
    }
    __syncthreads();

    f32x4 acc1[3][2], acc2[3][2];
#pragma unroll
    for (int s = 0; s < 3; s++)
#pragma unroll
        for (int ms = 0; ms < 2; ms++) {
            acc1[s][ms] = (f32x4){0.f, 0.f, 0.f, 0.f};
            acc2[s][ms] = (f32x4){0.f, 0.f, 0.f, 0.f};
        }

    const size_t tb = (size_t)(blockIdx.x * 4 + w);
    const int xk = r15 & 7;

    // ---- phase 1: gh = hb_in @ W1^T (nK=32) ----
    {
        const __bf16* wp0 = sW1 + (tb * 32) * 512 + lane * 8;
        const __bf16* wp1 = sW1 + ((tb + 64) * 32) * 512 + lane * 8;
        const __bf16* wp2 = sW1 + ((tb + 128) * 32) * 512 + lane * 8;
        const int ar0 = (r15 * 128) * 8, ar1 = ((16 + r15) * 128) * 8;
#pragma unroll 4
        for (int c = 0; c < 32; c++) {
            int us = (((c * 4 + q) ^ xk)) * 8;
            bfx8 a0 = *(const bfx8*)(sA1 + ar0 + us);
            bfx8 a1 = *(const bfx8*)(sA1 + ar1 + us);
            bfx8 w0 = *(const bfx8*)(wp0 + c * 512);
            bfx8 w1 = *(const bfx8*)(wp1 + c * 512);
            bfx8 w2 = *(const bfx8*)(wp2 + c * 512);
            acc1[0][0] = MFMA(a0, w0, acc1[0][0], 0, 0, 0);
            acc1[0][1] = MFMA(a1, w0, acc1[0][1], 0, 0, 0);
            acc1[1][0] = MFMA(a0, w1, acc1[1][0], 0, 0, 0);
            acc1[1][1] = MFMA(a1, w1, acc1[1][1], 0, 0, 0);
            acc1[2][0] = MFMA(a0, w2, acc1[2][0], 0, 0, 0);
            acc1[2][1] = MFMA(a1, w2, acc1[2][1], 0, 0, 0);
        }
    }
    // ---- phase 2: gi = A2 @ W2^T (nK=nK2) ----
    {
        const __bf16* wp0 = sW2 + (tb * (size_t)nK2) * 512 + lane * 8;
        const __bf16* wp1 = sW2 + ((tb + 64) * (size_t)nK2) * 512 + lane * 8;
        const __bf16* wp2 = sW2 + ((tb + 128) * (size_t)nK2) * 512 + lane * 8;
        const int ru = nK2 * 4;
        const int ar0 = (r15 * ru) * 8, ar1 = ((16 + r15) * ru) * 8;
#pragma unroll 4
        for (int c = 0; c < nK2; c++) {
            int us = (((c * 4 + q) ^ xk)) * 8;
            bfx8 a0 = *(const bfx8*)(sA2 + ar0 + us);
            bfx8 a1 = *(const bfx8*)(sA2 + ar1 + us);
            bfx8 w0 = *(const bfx8*)(wp0 + c * 512);
            bfx8 w1 = *(const bfx8*)(wp1 + c * 512);
            bfx8 w2 = *(const bfx8*)(wp2 + c * 512);
            acc2[0][0] = MFMA(a0, w0, acc2[0][0], 0, 0, 0);
            acc2[0][1] = MFMA(a1, w0, acc2[0][1], 0, 0, 0);
            acc2[1][0] = MFMA(a0, w1, acc2[1][0], 0, 0, 0);
            acc2[1][1] = MFMA(a1, w1, acc2[1][1], 0, 0, 0);
            acc2[2][0] = MFMA(a0, w2, acc2[2][0], 0, 0, 0);
            acc2[2][1] = MFMA(a1, w2, acc2[2][1], 0, 0, 0);
        }
    }
    // ---- GRU epilogue ----
    const int jj = j0 + w * 16 + r15;
    const float bb1[3] = {b1[jj], b1[1024 + jj], b1[2048 + jj]};
    const float bb2[3] = {b2[jj], b2[1024 + jj], b2[2048 + jj]};
#pragma unroll
    for (int ms = 0; ms < 2; ms++) {
#pragma unroll
        for (int reg = 0; reg < 4; reg++) {
            int b_ = m0 + ms * 16 + q * 4 + reg;
            float gh0 = acc1[0][ms][reg] + bb1[0];
            float gh1 = acc1[1][ms][reg] + bb1[1];
            float gh2 = acc1[2][ms][reg] + bb1[2];
            float gi0 = acc2[0][ms][reg] + bb2[0];
            float gi1 = acc2[1][ms][reg] + bb2[1];
            float gi2 = acc2[2][ms][reg] + bb2[2];
            float r = 1.f / (1.f + __expf(-(gi0 + gh0)));
            float z = 1.f / (1.f + __expf(-(gi1 + gh1)));
            float n = fast_tanh(gi2 + r * gh2);
            size_t off = (size_t)b_ * 1024 + jj;
            float hv = (1.f - z) * n + z * g_h[off];
            g_h[off] = hv;
            hb_out[off] = (__bf16)hv;
            if (enc_t >= 0) g_enc_ops[(size_t)enc_t * 524288 + off] = (__bf16)hv;
        }
    }
}

// ---------------------------------------------------------------------------
// Fused [hpart | logits] from h (bf16). grid (18, 16). bx<16: hpart col-tile;
// bx 16..17: logits (guard 70) -> out row lrow (skipped if lrow<0).
// ---------------------------------------------------------------------------
__global__ __launch_bounds__(256) void k_hl(
    const __bf16* __restrict__ src, const float* __restrict__ battn,
    const float* __restrict__ bout, int lrow, float* __restrict__ outp)
{
    __shared__ __bf16 sA[32 * 1024];
    const int tid = threadIdx.x;
    const int w = tid >> 6, lane = tid & 63;
    const int r15 = lane & 15, q = lane >> 4;
    const int bx = blockIdx.x, m0 = blockIdx.y * 32;

#pragma unroll
    for (int i = 0; i < 16; i++) {
        int lin = tid + i * 256;
        int r = lin >> 7, U = lin & 127;
        uint4 v = *(const uint4*)(src + (size_t)(m0 + r) * 1024 + U * 8);
        *(uint4*)(sA + (r * 128 + (U ^ (r & 7))) * 8) = v;
    }
    __syncthreads();

    const __bf16* sW;
    int n;
    if (bx < 16) {
        sW = g_sWattnA;
        n = bx * 64 + w * 16 + r15;
    } else {
        if (lrow < 0) return;
        sW = g_sWout;
        n = (bx - 16) * 64 + w * 16 + r15;
    }
    const size_t tb = (size_t)((bx < 16 ? bx : bx - 16) * 4 + w);
    const __bf16* wp = sW + (tb * 32) * 512 + lane * 8;
    const int xk = r15 & 7;
    const int ar0 = (r15 * 128) * 8, ar1 = ((16 + r15) * 128) * 8;

    f32x4 acc[2];
    acc[0] = (f32x4){0.f, 0.f, 0.f, 0.f};
    acc[1] = (f32x4){0.f, 0.f, 0.f, 0.f};
#pragma unroll 4
    for (int c = 0; c < 32; c++) {
        int us = (((c * 4 + q) ^ xk)) * 8;
        bfx8 a0 = *(const bfx8*)(sA + ar0 + us);
        bfx8 a1 = *(const bfx8*)(sA + ar1 + us);
        bfx8 wv = *(const bfx8*)(wp + c * 512);
        acc[0] = MFMA(a0, wv, acc[0], 0, 0, 0);
        acc[1] = MFMA(a1, wv, acc[1], 0, 0, 0);
    }

    if (bx < 16) {
        float bv = battn[n];
#pragma unroll
        for (int ms = 0; ms < 2; ms++)
#pragma unroll
            for (int reg = 0; reg < 4; reg++)
                g_hpart[(size_t)(m0 + ms * 16 + q * 4 + reg) * 1024 + n] =
                    acc[ms][reg] + bv;
    } else if (n < 70) {
        float bv = bout[n];
#pragma unroll
        for (int ms = 0; ms < 2; ms++)
#pragma unroll
            for (int reg = 0; reg < 4; reg++)
                outp[(size_t)lrow * 35840 +
                     (size_t)(m0 + ms * 16 + q * 4 + reg) * 70 + n] =
                    acc[ms][reg] + bv;
    }
}

// ---------------------------------------------------------------------------
// Attention step: x-select + embed + scores + softmax + alpha out + ctx.
// One block per batch b.
// ---------------------------------------------------------------------------
__global__ __launch_bounds__(256) void k_attn(
    int j, const int* __restrict__ target, const int* __restrict__ tf,
    const float* __restrict__ v_attn, float* __restrict__ out)
{
    const int b = blockIdx.x, tid = threadIdx.x;
    const int lane = tid & 63, wave = tid >> 6;
    __shared__ float sc[32], sal[32];
    __shared__ int sx;
    if (wave == 0) {
        int xv;
        if (j == 0) xv = target[b];
        else if (*tf) xv = target[j * 512 + b];
        else {
            const float* row = out + (size_t)j * 35840 + b * 70;
            float bv = row[lane]; int bi = lane;
            if (lane < 6) {
                float v2 = row[lane + 64];
                if (v2 > bv) { bv = v2; bi = lane + 64; }
            }
#pragma unroll
            for (int off = 32; off; off >>= 1) {
                float ov = __shfl_down(bv, off);
                int   oi = __shfl_down(bi, off);
                if (ov > bv || (ov == bv && oi < bi)) { bv = ov; bi = oi; }
            }
            xv = bi;
        }
        if (lane == 0) sx = (xv < 0) ? 0 : (xv > 69 ? 69 : xv);
    }
    float hpv[16], vsv[16];
    {
        const float* hp = g_hpart + (size_t)b * 1024;
#pragma unroll
        for (int u = 0; u < 8; u++) {
            hpv[u]     = hp[lane * 8 + u];
            hpv[8 + u] = hp[512 + lane * 8 + u];
            vsv[u]     = v_attn[lane * 8 + u];
            vsv[8 + u] = v_attn[512 + lane * 8 + u];
        }
    }
    __syncthreads();
    g_Adec[(size_t)b * 1280 + 1024 + tid] = g_embt[sx * 256 + tid];
    for (int s = wave * 8; s < wave * 8 + 8; s++) {
        const __bf16* ep = g_enc_part + ((size_t)s * 512 + b) * 1024;
        bfx8 e0 = *(const bfx8*)(ep + lane * 8);
        bfx8 e1 = *(const bfx8*)(ep + 512 + lane * 8);
        float part = 0.f;
#pragma unroll
        for (int u = 0; u < 8; u++) {
            part += vsv[u]     * fast_tanh((float)e0[u] + hpv[u]);
            part += vsv[8 + u] * fast_tanh((float)e1[u] + hpv[8 + u]);
        }
#pragma unroll
        for (int off = 32; off; off >>= 1) part += __shfl_down(part, off);
        if (lane == 0) sc[s] = part;
    }
    __syncthreads();
    float mx = sc[0];
#pragma unroll
    for (int s = 1; s < 32; s++) mx = fmaxf(mx, sc[s]);
    float den = 0.f;
#pragma unroll
    for (int s = 0; s < 32; s++) den += __expf(sc[s] - mx);
    float rden = 1.f / den;
    if (tid < 32) {
        float al = __expf(sc[tid] - mx) * rden;
        sal[tid] = al;
        out[1146880 + (size_t)j * 16384 + b * 32 + tid] = al;
    }
    __syncthreads();
    float c0 = 0, c1 = 0, c2 = 0, c3 = 0;
    const __bf16* eo = g_enc_ops + (size_t)b * 1024 + tid * 4;
#pragma unroll 4
    for (int s = 0; s < 32; s++) {
        bfx4 e = *(const bfx4*)(eo + (size_t)s * 524288);
        float al = sal[s];
        c0 += al * (float)e[0]; c1 += al * (float)e[1];
        c2 += al * (float)e[2]; c3 += al * (float)e[3];
    }
    bfx4 o = {(__bf16)c0, (__bf16)c1, (__bf16)c2, (__bf16)c3};
    *(bfx4*)(&g_Adec[(size_t)b * 1280 + tid * 4]) = o;
}

// ---------------------------------------------------------------------------
extern "C" void kernel_launch(void* const* d_in, const int* in_sizes, int n_in,
                              void* d_out, int out_size, void* d_ws, size_t ws_size,
                              hipStream_t stream)
{
    const int*   source   = (const int*)d_in[0];
    const int*   target   = (const int*)d_in[1];
    const int*   tf       = (const int*)d_in[2];
    const float* emb_src  = (const float*)d_in[3];
    const float* W_ih_enc = (const float*)d_in[4];
    const float* W_hh_enc = (const float*)d_in[5];
    const float* b_ih_enc = (const float*)d_in[6];
    const float* b_hh_enc = (const float*)d_in[7];
    const float* emb_tgt  = (const float*)d_in[8];
    const float* W_attn   = (const float*)d_in[9];
    const float* b_attn   = (const float*)d_in[10];
    const float* v_attn   = (const float*)d_in[11];
    const float* W_ih_dec = (const float*)d_in[12];
    const float* W_hh_dec = (const float*)d_in[13];
    const float* b_ih_dec = (const float*)d_in[14];
    const float* b_hh_dec = (const float*)d_in[15];
    const float* W_out    = (const float*)d_in[16];
    const float* b_out    = (const float*)d_in[17];
    float* out = (float*)d_out;

    void *p_hb, *p_sWhhe, *p_sWihe, *p_sWhhd, *p_sWihd, *p_sWattnA, *p_sWout,
         *p_embs, *p_embt, *p_WattnT, *p_enc_ops, *p_enc_part;
    hipGetSymbolAddress(&p_hb,       HIP_SYMBOL(g_hb));
    hipGetSymbolAddress(&p_sWhhe,    HIP_SYMBOL(g_sWhhe));
    hipGetSymbolAddress(&p_sWihe,    HIP_SYMBOL(g_sWihe));
    hipGetSymbolAddress(&p_sWhhd,    HIP_SYMBOL(g_sWhhd));
    hipGetSymbolAddress(&p_sWihd,    HIP_SYMBOL(g_sWihd));
    hipGetSymbolAddress(&p_sWattnA,  HIP_SYMBOL(g_sWattnA));
    hipGetSymbolAddress(&p_sWout,    HIP_SYMBOL(g_sWout));
    hipGetSymbolAddress(&p_embs,     HIP_SYMBOL(g_embs));
    hipGetSymbolAddress(&p_embt,     HIP_SYMBOL(g_embt));
    hipGetSymbolAddress(&p_WattnT,   HIP_SYMBOL(g_WattnT));
    hipGetSymbolAddress(&p_enc_ops,  HIP_SYMBOL(g_enc_ops));
    hipGetSymbolAddress(&p_enc_part, HIP_SYMBOL(g_enc_part));
    __bf16* hb0 = (__bf16*)p_hb;
    __bf16* hb1 = hb0 + 512 * 1024;

    // ---- one-time setup ----
    k_cvt<<<16, 256, 0, stream>>>(emb_src, (__bf16*)p_embs, 64 * 256 / 4);
    k_cvt<<<18, 256, 0, stream>>>(emb_tgt, (__bf16*)p_embt, 70 * 256 / 4);
    swz_rm<<<1536, 256, 0, stream>>>(W_hh_enc, (__bf16*)p_sWhhe, 32, 393216);
    swz_rm<<<384,  256, 0, stream>>>(W_ih_enc, (__bf16*)p_sWihe, 8,  98304);
    swz_rm<<<1536, 256, 0, stream>>>(W_hh_dec, (__bf16*)p_sWhhd, 32, 393216);
    swz_rm<<<1920, 256, 0, stream>>>(W_ih_dec, (__bf16*)p_sWihd, 40, 491520);
    swz_cm<<<512,  256, 0, stream>>>(W_attn, (__bf16*)p_sWattnA, 32, 1024, 1024, 131072);
    swz_cm<<<64,   256, 0, stream>>>(W_out,  (__bf16*)p_sWout,   32, 70,   70,   16384);
    k_transpose<<<dim3(32, 64), 256, 0, stream>>>(W_attn);
    k_init<<<2048, 256, 0, stream>>>(out);

    // -------- Encoder: 32 steps --------
    for (int t = 0; t < 32; t++) {
        __bf16* hin  = (t & 1) ? hb1 : hb0;
        __bf16* hout = (t & 1) ? hb0 : hb1;
        gru_step<<<dim3(16, 16), 256, 0, stream>>>(
            hin, hout, (__bf16*)p_sWhhe, b_hh_enc,
            (__bf16*)p_sWihe, b_ih_enc, 8, source + t * 512, t);
    }
    // h_enc lands in hb0

    // enc_part = enc_ops @ W_attn[H:2H]^T
    gemm_bt<<<dim3(16, 256), 256, 0, stream>>>(
        (__bf16*)p_enc_ops, 1024, (__bf16*)p_WattnT + 1024, 2048, nullptr,
        p_enc_part, 1024, 1, 1024, 1 << 30);

    // hpart for step 0
    k_hl<<<dim3(18, 16), 256, 0, stream>>>(hb0, b_attn, b_out, -1, out);

    // -------- Decoder: 31 steps --------
    for (int j = 0; j < 31; j++) {
        __bf16* hin  = (j & 1) ? hb1 : hb0;
        __bf16* hout = (j & 1) ? hb0 : hb1;
        k_attn<<<512, 256, 0, stream>>>(j, target, tf, v_attn, out);
        gru_step<<<dim3(16, 16), 256, 0, stream>>>(
            hin, hout, (__bf16*)p_sWhhd, b_hh_dec,
            (__bf16*)p_sWihd, b_ih_dec, 40, nullptr, -1);
        k_hl<<<dim3(18, 16), 256, 0, stream>>>(hout, b_attn, b_out, j + 1, out);
    }
}

// Round 8
// 2523.293 us; speedup vs baseline: 6.6673x; 1.0583x over previous
//
#include <hip/hip_runtime.h>
#include <hip/hip_bf16.h>

typedef __bf16 bfx8 __attribute__((ext_vector_type(8)));
typedef __bf16 bfx4 __attribute__((ext_vector_type(4)));
typedef float f32x4 __attribute__((ext_vector_type(4)));

#define MFMA __builtin_amdgcn_mfma_f32_16x16x32_bf16

// Dims: S=32 T=32 B=512 H=1024 E=256 A=1024 VS=64 VT=70 START=1
// f32 in/out; MFMA on bf16. Weights pre-swizzled fragment-major (64 lanes x
// 16B contiguous per 16x32 fragment) -> coalesced 1KB wave loads. A-tiles
// staged once into XOR-swizzled LDS. gru_step: 512 thr, wave-specialized
// (waves 0-3 gh-GEMM, 4-7 gi-GEMM concurrently; gi handed over via LDS).

__device__ __attribute__((aligned(256))) float  g_h[512 * 1024];
__device__ __attribute__((aligned(256))) float  g_hpart[512 * 1024];
__device__ __attribute__((aligned(256))) __bf16 g_hb[2][512 * 1024];
__device__ __attribute__((aligned(256))) __bf16 g_Adec[512 * 1280];
__device__ __attribute__((aligned(256))) __bf16 g_enc_ops[(size_t)32 * 512 * 1024];
__device__ __attribute__((aligned(256))) __bf16 g_enc_part[(size_t)32 * 512 * 1024];
__device__ __attribute__((aligned(256))) __bf16 g_WattnT[(size_t)1024 * 2048];  // row-major, for gemm_bt
__device__ __attribute__((aligned(256))) __bf16 g_sWhhe[(size_t)3072 * 1024];   // fragment-major
__device__ __attribute__((aligned(256))) __bf16 g_sWihe[(size_t)3072 * 256];
__device__ __attribute__((aligned(256))) __bf16 g_sWhhd[(size_t)3072 * 1024];
__device__ __attribute__((aligned(256))) __bf16 g_sWihd[(size_t)3072 * 1280];
__device__ __attribute__((aligned(256))) __bf16 g_sWattnA[(size_t)1024 * 1024];
__device__ __attribute__((aligned(256))) __bf16 g_sWout[(size_t)128 * 1024];
__device__ __attribute__((aligned(256))) __bf16 g_embs[64 * 256];
__device__ __attribute__((aligned(256))) __bf16 g_embt[70 * 256];

__device__ __forceinline__ float fast_tanh(float x) {
    float cx = fminf(fmaxf(x, -15.f), 15.f);
    float e = __expf(-2.f * cx);
    return (1.f - e) / (1.f + e);
}

// ---------------------------------------------------------------------------
__global__ void k_cvt(const float* __restrict__ src, __bf16* __restrict__ dst,
                      int n4)
{
    int i = blockIdx.x * 256 + threadIdx.x;
    if (i >= n4) return;
    float4 v = ((const float4*)src)[i];
    __bf16 o[4] = {(__bf16)v.x, (__bf16)v.y, (__bf16)v.z, (__bf16)v.w};
    *(ushort2*)(dst + 4 * i) = *(ushort2*)o;
    *(ushort2*)(dst + 4 * i + 2) = *(ushort2*)(o + 2);
}

// Row-major f32 W[R][K] -> fragment-major bf16.
__global__ void swz_rm(const float* __restrict__ W, __bf16* __restrict__ out,
                       int nK, int total)
{
    int gid = blockIdx.x * 256 + threadIdx.x;
    if (gid >= total) return;
    int F = gid >> 6, L = gid & 63;
    int t = F / nK, c = F - t * nK;
    int K = nK * 32;
    const float* s = W + (size_t)(t * 16 + (L & 15)) * K + c * 32 + (L >> 4) * 8;
    __bf16 o[8];
#pragma unroll
    for (int u = 0; u < 8; u++) o[u] = (__bf16)s[u];
    *(uint4*)(out + (size_t)gid * 8) = *(uint4*)o;
}

// Column-gather: logical W'[n][k] = W[k*ldsrc + n]; n>=nguard -> 0.
__global__ void swz_cm(const float* __restrict__ W, __bf16* __restrict__ out,
                       int nK, int ldsrc, int nguard, int total)
{
    int gid = blockIdx.x * 256 + threadIdx.x;
    if (gid >= total) return;
    int F = gid >> 6, L = gid & 63;
    int t = F / nK, c = F - t * nK;
    int n = t * 16 + (L & 15);
    int k = c * 32 + (L >> 4) * 8;
    __bf16 o[8];
#pragma unroll
    for (int u = 0; u < 8; u++)
        o[u] = (n < nguard) ? (__bf16)W[(size_t)(k + u) * ldsrc + n] : (__bf16)0.f;
    *(uint4*)(out + (size_t)gid * 8) = *(uint4*)o;
}

// W_attn f32 (2048,1024) -> g_WattnT bf16 (1024,2048) row-major
__global__ __launch_bounds__(256) void k_transpose(const float* __restrict__ Wsrc)
{
    __shared__ float t[32][33];
    int bx = blockIdx.x, by = blockIdx.y;
    int lx = threadIdx.x & 31, ly = threadIdx.x >> 5;
    for (int i = 0; i < 32; i += 8)
        t[ly + i][lx] = Wsrc[(size_t)(by * 32 + ly + i) * 1024 + bx * 32 + lx];
    __syncthreads();
    for (int i = 0; i < 32; i += 8)
        g_WattnT[(size_t)(bx * 32 + ly + i) * 2048 + by * 32 + lx] =
            (__bf16)t[lx][ly + i];
}

__global__ void k_init(float* __restrict__ out)
{
    int idx = blockIdx.x * 256 + threadIdx.x;
    if (idx < 512 * 1024) { g_h[idx] = 0.f; g_hb[0][idx] = (__bf16)0.f; }
    if (idx < 512 * 70) out[idx] = (idx % 70 == 1) ? 1.f : 0.f;
}

// ---------------------------------------------------------------------------
// gemm_bt (LDS-staged) -- only for the one-shot enc_part GEMM.
// ---------------------------------------------------------------------------
__global__ __launch_bounds__(256) void gemm_bt(
    const __bf16* __restrict__ Amat, int lda,
    const __bf16* __restrict__ Wmat, int ldw,
    const float* __restrict__ bias,
    void* __restrict__ Cout, int ldc, int cmode, int K, int nguard)
{
    __shared__ __bf16 As[64][40];
    __shared__ __bf16 Ws[64][40];
    const int tid  = threadIdx.x;
    const int m0   = blockIdx.y * 64;
    const int n0   = blockIdx.x * 64;
    const int wave = tid >> 6;
    const int lane = tid & 63;
    const int srow = tid >> 2;
    const int scol = (tid & 3) << 3;

    const __bf16* aptr = Amat + (size_t)(m0 + srow) * lda + scol;
    const __bf16* wptr = Wmat + (size_t)(n0 + srow) * ldw + scol;

    f32x4 acc[4];
#pragma unroll
    for (int i = 0; i < 4; i++) acc[i] = (f32x4){0.f, 0.f, 0.f, 0.f};

    const int r15 = lane & 15;
    const int kk  = (lane >> 4) << 3;

    for (int k0 = 0; k0 < K; k0 += 32) {
        uint4 av = *(const uint4*)(aptr + k0);
        uint4 wv = *(const uint4*)(wptr + k0);
        __syncthreads();
        *(uint4*)(&As[srow][scol]) = av;
        *(uint4*)(&Ws[srow][scol]) = wv;
        __syncthreads();
        bfx8 a = *(const bfx8*)(&As[wave * 16 + r15][kk]);
#pragma unroll
        for (int n = 0; n < 4; n++) {
            bfx8 b = *(const bfx8*)(&Ws[n * 16 + r15][kk]);
            acc[n] = MFMA(a, b, acc[n], 0, 0, 0);
        }
    }

    const int rowb = m0 + wave * 16 + (lane >> 4) * 4;
#pragma unroll
    for (int n = 0; n < 4; n++) {
        int c = n0 + n * 16 + r15;
        if (c >= nguard) continue;
        float bv = bias ? bias[c] : 0.f;
#pragma unroll
        for (int r = 0; r < 4; r++) {
            float v = acc[n][r] + bv;
            size_t off = (size_t)(rowb + r) * ldc + c;
            if (cmode == 0) ((float*)Cout)[off] = v;
            else            ((__bf16*)Cout)[off] = (__bf16)v;
        }
    }
}

// ---------------------------------------------------------------------------
// Fused GRU step v3: 512 threads, wave-specialized. grid (16 j, 16 m) = 256
// blocks (1/CU, 8 waves/CU). Waves 0-3: gh = hb_in @ W1^T (j-sub w, 32 rows,
// 3 gates). Waves 4-7: gi = A2 @ W2^T (j-sub w-4). gi handed to waves 0-3 via
// LDS (sA2 reused); epilogue by waves 0-3. K-loops barrier-free; W traffic
// identical to the 4-wave version (each fragment read once per block).
// ---------------------------------------------------------------------------
__global__ __launch_bounds__(512, 1) void gru_step(
    const __bf16* __restrict__ hb_in, __bf16* __restrict__ hb_out,
    const __bf16* __restrict__ sW1, const float* __restrict__ b1,
    const __bf16* __restrict__ sW2, const float* __restrict__ b2,
    int nK2, const int* __restrict__ src_t, int enc_t)
{
    __shared__ __bf16 sA1[32 * 1024];   // 64 KB
    __shared__ __bf16 sA2[32 * 1280];   // 80 KB (reused as f32 gi buffer)
    const int tid = threadIdx.x;
    const int w = tid >> 6, lane = tid & 63;
    const int r15 = lane & 15, q = lane >> 4;
    const int j0 = blockIdx.x * 64, m0 = blockIdx.y * 32;
    const int jsub = w & 3;

    // ---- stage A1: 32 rows x 128 16B-units, xor-swizzled ----
#pragma unroll
    for (int i = 0; i < 8; i++) {
        int lin = tid + i * 512;
        int r = lin >> 7, U = lin & 127;
        uint4 v = *(const uint4*)(hb_in + (size_t)(m0 + r) * 1024 + U * 8);
        *(uint4*)(sA1 + (r * 128 + (U ^ (r & 7))) * 8) = v;
    }
    // ---- stage A2 ----
    if (src_t) {  // encoder: emb gather, 32 x 32 units
#pragma unroll
        for (int i = 0; i < 2; i++) {
            int lin = tid + i * 512;
            int r = lin >> 5, U = lin & 31;
            int sv = src_t[m0 + r];
            sv = (sv < 0) ? 0 : (sv > 63 ? 63 : sv);
            uint4 v = *(const uint4*)(g_embs + sv * 256 + U * 8);
            *(uint4*)(sA2 + (r * 32 + (U ^ (r & 7))) * 8) = v;
        }
    } else {      // decoder: Adec, 32 x 160 units
        for (int lin = tid; lin < 32 * 160; lin += 512) {
            int r = lin / 160, U = lin - r * 160;
            uint4 v = *(const uint4*)(g_Adec + (size_t)(m0 + r) * 1280 + U * 8);
            *(uint4*)(sA2 + (r * 160 + (U ^ (r & 7))) * 8) = v;
        }
    }
    __syncthreads();

    const size_t tb = (size_t)(blockIdx.x * 4 + jsub);
    const int xk = r15 & 7;
    f32x4 acc[3][2];
#pragma unroll
    for (int s = 0; s < 3; s++)
#pragma unroll
        for (int ms = 0; ms < 2; ms++) acc[s][ms] = (f32x4){0.f, 0.f, 0.f, 0.f};

    if (w < 4) {
        // ---- phase 1: gh (K=1024, 32 k-frags) ----
        const __bf16* wp0 = sW1 + (tb * 32) * 512 + lane * 8;
        const __bf16* wp1 = sW1 + ((tb + 64) * 32) * 512 + lane * 8;
        const __bf16* wp2 = sW1 + ((tb + 128) * 32) * 512 + lane * 8;
        const int ar0 = r15 * 1024, ar1 = (16 + r15) * 1024;
#pragma unroll 4
        for (int c = 0; c < 32; c++) {
            int us = ((c * 4 + q) ^ xk) * 8;
            bfx8 a0 = *(const bfx8*)(sA1 + ar0 + us);
            bfx8 a1 = *(const bfx8*)(sA1 + ar1 + us);
            bfx8 w0 = *(const bfx8*)(wp0 + c * 512);
            bfx8 w1 = *(const bfx8*)(wp1 + c * 512);
            bfx8 w2 = *(const bfx8*)(wp2 + c * 512);
            acc[0][0] = MFMA(a0, w0, acc[0][0], 0, 0, 0);
            acc[0][1] = MFMA(a1, w0, acc[0][1], 0, 0, 0);
            acc[1][0] = MFMA(a0, w1, acc[1][0], 0, 0, 0);
            acc[1][1] = MFMA(a1, w1, acc[1][1], 0, 0, 0);
            acc[2][0] = MFMA(a0, w2, acc[2][0], 0, 0, 0);
            acc[2][1] = MFMA(a1, w2, acc[2][1], 0, 0, 0);
        }
    } else {
        // ---- phase 2: gi (K = nK2*32) ----
        const __bf16* wp0 = sW2 + (tb * (size_t)nK2) * 512 + lane * 8;
        const __bf16* wp1 = sW2 + ((tb + 64) * (size_t)nK2) * 512 + lane * 8;
        const __bf16* wp2 = sW2 + ((tb + 128) * (size_t)nK2) * 512 + lane * 8;
        const int ru = nK2 * 4;
        const int ar0 = r15 * ru * 8, ar1 = (16 + r15) * ru * 8;
#pragma unroll 4
        for (int c = 0; c < nK2; c++) {
            int us = ((c * 4 + q) ^ xk) * 8;
            bfx8 a0 = *(const bfx8*)(sA2 + ar0 + us);
            bfx8 a1 = *(const bfx8*)(sA2 + ar1 + us);
            bfx8 w0 = *(const bfx8*)(wp0 + c * 512);
            bfx8 w1 = *(const bfx8*)(wp1 + c * 512);
            bfx8 w2 = *(const bfx8*)(wp2 + c * 512);
            acc[0][0] = MFMA(a0, w0, acc[0][0], 0, 0, 0);
            acc[0][1] = MFMA(a1, w0, acc[0][1], 0, 0, 0);
            acc[1][0] = MFMA(a0, w1, acc[1][0], 0, 0, 0);
            acc[1][1] = MFMA(a1, w1, acc[1][1], 0, 0, 0);
            acc[2][0] = MFMA(a0, w2, acc[2][0], 0, 0, 0);
            acc[2][1] = MFMA(a1, w2, acc[2][1], 0, 0, 0);
        }
    }
    __syncthreads();  // all K-loops done; sA2 now dead -> reuse for gi
    float* sGi = (float*)sA2;
    if (w >= 4) {
#pragma unroll
        for (int s = 0; s < 3; s++)
#pragma unroll
            for (int ms = 0; ms < 2; ms++)
#pragma unroll
                for (int reg = 0; reg < 4; reg++)
                    sGi[((s * 4 + jsub) * 32 + ms * 16 + q * 4 + reg) * 16 + r15] =
                        acc[s][ms][reg];
    }
    __syncthreads();
    if (w < 4) {
        const int jj = j0 + jsub * 16 + r15;
        const float bb1[3] = {b1[jj], b1[1024 + jj], b1[2048 + jj]};
        const float bb2[3] = {b2[jj], b2[1024 + jj], b2[2048 + jj]};
#pragma unroll
        for (int ms = 0; ms < 2; ms++) {
#pragma unroll
            for (int reg = 0; reg < 4; reg++) {
                int bl = ms * 16 + q * 4 + reg;
                int b_ = m0 + bl;
                float gh0 = acc[0][ms][reg] + bb1[0];
                float gh1 = acc[1][ms][reg] + bb1[1];
                float gh2 = acc[2][ms][reg] + bb1[2];
                float gi0 = sGi[((0 * 4 + jsub) * 32 + bl) * 16 + r15] + bb2[0];
                float gi1 = sGi[((1 * 4 + jsub) * 32 + bl) * 16 + r15] + bb2[1];
                float gi2 = sGi[((2 * 4 + jsub) * 32 + bl) * 16 + r15] + bb2[2];
                float r = 1.f / (1.f + __expf(-(gi0 + gh0)));
                float z = 1.f / (1.f + __expf(-(gi1 + gh1)));
                float n = fast_tanh(gi2 + r * gh2);
                size_t off = (size_t)b_ * 1024 + jj;
                float hv = (1.f - z) * n + z * g_h[off];
                g_h[off] = hv;
                hb_out[off] = (__bf16)hv;
                if (enc_t >= 0)
                    g_enc_ops[(size_t)enc_t * 524288 + off] = (__bf16)hv;
            }
        }
    }
}

// ---------------------------------------------------------------------------
// Fused [hpart | logits] from h (bf16). grid (18, 16). bx<16: hpart col-tile;
// bx 16..17: logits (guard 70) -> out row lrow (skipped if lrow<0).
// ---------------------------------------------------------------------------
__global__ __launch_bounds__(256) void k_hl(
    const __bf16* __restrict__ src, const float* __restrict__ battn,
    const float* __restrict__ bout, int lrow, float* __restrict__ outp)
{
    __shared__ __bf16 sA[32 * 1024];
    const int tid = threadIdx.x;
    const int w = tid >> 6, lane = tid & 63;
    const int r15 = lane & 15, q = lane >> 4;
    const int bx = blockIdx.x, m0 = blockIdx.y * 32;

#pragma unroll
    for (int i = 0; i < 16; i++) {
        int lin = tid + i * 256;
        int r = lin >> 7, U = lin & 127;
        uint4 v = *(const uint4*)(src + (size_t)(m0 + r) * 1024 + U * 8);
        *(uint4*)(sA + (r * 128 + (U ^ (r & 7))) * 8) = v;
    }
    __syncthreads();

    const __bf16* sW;
    int n;
    if (bx < 16) {
        sW = g_sWattnA;
        n = bx * 64 + w * 16 + r15;
    } else {
        if (lrow < 0) return;
        sW = g_sWout;
        n = (bx - 16) * 64 + w * 16 + r15;
    }
    const size_t tb = (size_t)((bx < 16 ? bx : bx - 16) * 4 + w);
    const __bf16* wp = sW + (tb * 32) * 512 + lane * 8;
    const int xk = r15 & 7;
    const int ar0 = r15 * 1024, ar1 = (16 + r15) * 1024;

    f32x4 acc[2];
    acc[0] = (f32x4){0.f, 0.f, 0.f, 0.f};
    acc[1] = (f32x4){0.f, 0.f, 0.f, 0.f};
#pragma unroll 4
    for (int c = 0; c < 32; c++) {
        int us = ((c * 4 + q) ^ xk) * 8;
        bfx8 a0 = *(const bfx8*)(sA + ar0 + us);
        bfx8 a1 = *(const bfx8*)(sA + ar1 + us);
        bfx8 wv = *(const bfx8*)(wp + c * 512);
        acc[0] = MFMA(a0, wv, acc[0], 0, 0, 0);
        acc[1] = MFMA(a1, wv, acc[1], 0, 0, 0);
    }

    if (bx < 16) {
        float bv = battn[n];
#pragma unroll
        for (int ms = 0; ms < 2; ms++)
#pragma unroll
            for (int reg = 0; reg < 4; reg++)
                g_hpart[(size_t)(m0 + ms * 16 + q * 4 + reg) * 1024 + n] =
                    acc[ms][reg] + bv;
    } else if (n < 70) {
        float bv = bout[n];
#pragma unroll
        for (int ms = 0; ms < 2; ms++)
#pragma unroll
            for (int reg = 0; reg < 4; reg++)
                outp[(size_t)lrow * 35840 +
                     (size_t)(m0 + ms * 16 + q * 4 + reg) * 70 + n] =
                    acc[ms][reg] + bv;
    }
}

// ---------------------------------------------------------------------------
// Attention step: x-select + embed + scores + softmax + alpha out + ctx.
// One block per batch b.
// ---------------------------------------------------------------------------
__global__ __launch_bounds__(256) void k_attn(
    int j, const int* __restrict__ target, const int* __restrict__ tf,
    const float* __restrict__ v_attn, float* __restrict__ out)
{
    const int b = blockIdx.x, tid = threadIdx.x;
    const int lane = tid & 63, wave = tid >> 6;
    __shared__ float sc[32], sal[32];
    __shared__ int sx;
    if (wave == 0) {
        int xv;
        if (j == 0) xv = target[b];
        else if (*tf) xv = target[j * 512 + b];
        else {
            const float* row = out + (size_t)j * 35840 + b * 70;
            float bv = row[lane]; int bi = lane;
            if (lane < 6) {
                float v2 = row[lane + 64];
                if (v2 > bv) { bv = v2; bi = lane + 64; }
            }
#pragma unroll
            for (int off = 32; off; off >>= 1) {
                float ov = __shfl_down(bv, off);
                int   oi = __shfl_down(bi, off);
                if (ov > bv || (ov == bv && oi < bi)) { bv = ov; bi = oi; }
            }
            xv = bi;
        }
        if (lane == 0) sx = (xv < 0) ? 0 : (xv > 69 ? 69 : xv);
    }
    float hpv[16], vsv[16];
    {
        const float* hp = g_hpart + (size_t)b * 1024;
#pragma unroll
        for (int u = 0; u < 8; u++) {
            hpv[u]     = hp[lane * 8 + u];
            hpv[8 + u] = hp[512 + lane * 8 + u];
            vsv[u]     = v_attn[lane * 8 + u];
            vsv[8 + u] = v_attn[512 + lane * 8 + u];
        }
    }
    __syncthreads();
    g_Adec[(size_t)b * 1280 + 1024 + tid] = g_embt[sx * 256 + tid];
    for (int s = wave * 8; s < wave * 8 + 8; s++) {
        const __bf16* ep = g_enc_part + ((size_t)s * 512 + b) * 1024;
        bfx8 e0 = *(const bfx8*)(ep + lane * 8);
        bfx8 e1 = *(const bfx8*)(ep + 512 + lane * 8);
        float part = 0.f;
#pragma unroll
        for (int u = 0; u < 8; u++) {
            part += vsv[u]     * fast_tanh((float)e0[u] + hpv[u]);
            part += vsv[8 + u] * fast_tanh((float)e1[u] + hpv[8 + u]);
        }
#pragma unroll
        for (int off = 32; off; off >>= 1) part += __shfl_down(part, off);
        if (lane == 0) sc[s] = part;
    }
    __syncthreads();
    float mx = sc[0];
#pragma unroll
    for (int s = 1; s < 32; s++) mx = fmaxf(mx, sc[s]);
    float den = 0.f;
#pragma unroll
    for (int s = 0; s < 32; s++) den += __expf(sc[s] - mx);
    float rden = 1.f / den;
    if (tid < 32) {
        float al = __expf(sc[tid] - mx) * rden;
        sal[tid] = al;
        out[1146880 + (size_t)j * 16384 + b * 32 + tid] = al;
    }
    __syncthreads();
    float c0 = 0, c1 = 0, c2 = 0, c3 = 0;
    const __bf16* eo = g_enc_ops + (size_t)b * 1024 + tid * 4;
#pragma unroll 4
    for (int s = 0; s < 32; s++) {
        bfx4 e = *(const bfx4*)(eo + (size_t)s * 524288);
        float al = sal[s];
        c0 += al * (float)e[0]; c1 += al * (float)e[1];
        c2 += al * (float)e[2]; c3 += al * (float)e[3];
    }
    bfx4 o = {(__bf16)c0, (__bf16)c1, (__bf16)c2, (__bf16)c3};
    *(bfx4*)(&g_Adec[(size_t)b * 1280 + tid * 4]) = o;
}

// ---------------------------------------------------------------------------
extern "C" void kernel_launch(void* const* d_in, const int* in_sizes, int n_in,
                              void* d_out, int out_size, void* d_ws, size_t ws_size,
                              hipStream_t stream)
{
    const int*   source   = (const int*)d_in[0];
    const int*   target   = (const int*)d_in[1];
    const int*   tf       = (const int*)d_in[2];
    const float* emb_src  = (const float*)d_in[3];
    const float* W_ih_enc = (const float*)d_in[4];
    const float* W_hh_enc = (const float*)d_in[5];
    const float* b_ih_enc = (const float*)d_in[6];
    const float* b_hh_enc = (const float*)d_in[7];
    const float* emb_tgt  = (const float*)d_in[8];
    const float* W_attn   = (const float*)d_in[9];
    const float* b_attn   = (const float*)d_in[10];
    const float* v_attn   = (const float*)d_in[11];
    const float* W_ih_dec = (const float*)d_in[12];
    const float* W_hh_dec = (const float*)d_in[13];
    const float* b_ih_dec = (const float*)d_in[14];
    const float* b_hh_dec = (const float*)d_in[15];
    const float* W_out    = (const float*)d_in[16];
    const float* b_out    = (const float*)d_in[17];
    float* out = (float*)d_out;

    void *p_hb, *p_sWhhe, *p_sWihe, *p_sWhhd, *p_sWihd, *p_sWattnA, *p_sWout,
         *p_embs, *p_embt, *p_WattnT, *p_enc_ops, *p_enc_part;
    hipGetSymbolAddress(&p_hb,       HIP_SYMBOL(g_hb));
    hipGetSymbolAddress(&p_sWhhe,    HIP_SYMBOL(g_sWhhe));
    hipGetSymbolAddress(&p_sWihe,    HIP_SYMBOL(g_sWihe));
    hipGetSymbolAddress(&p_sWhhd,    HIP_SYMBOL(g_sWhhd));
    hipGetSymbolAddress(&p_sWihd,    HIP_SYMBOL(g_sWihd));
    hipGetSymbolAddress(&p_sWattnA,  HIP_SYMBOL(g_sWattnA));
    hipGetSymbolAddress(&p_sWout,    HIP_SYMBOL(g_sWout));
    hipGetSymbolAddress(&p_embs,     HIP_SYMBOL(g_embs));
    hipGetSymbolAddress(&p_embt,     HIP_SYMBOL(g_embt));
    hipGetSymbolAddress(&p_WattnT,   HIP_SYMBOL(g_WattnT));
    hipGetSymbolAddress(&p_enc_ops,  HIP_SYMBOL(g_enc_ops));
    hipGetSymbolAddress(&p_enc_part, HIP_SYMBOL(g_enc_part));
    __bf16* hb0 = (__bf16*)p_hb;
    __bf16* hb1 = hb0 + 512 * 1024;

    // ---- one-time setup ----
    k_cvt<<<16, 256, 0, stream>>>(emb_src, (__bf16*)p_embs, 64 * 256 / 4);
    k_cvt<<<18, 256, 0, stream>>>(emb_tgt, (__bf16*)p_embt, 70 * 256 / 4);
    swz_rm<<<1536, 256, 0, stream>>>(W_hh_enc, (__bf16*)p_sWhhe, 32, 393216);
    swz_rm<<<384,  256, 0, stream>>>(W_ih_enc, (__bf16*)p_sWihe, 8,  98304);
    swz_rm<<<1536, 256, 0, stream>>>(W_hh_dec, (__bf16*)p_sWhhd, 32, 393216);
    swz_rm<<<1920, 256, 0, stream>>>(W_ih_dec, (__bf16*)p_sWihd, 40, 491520);
    swz_cm<<<512,  256, 0, stream>>>(W_attn, (__bf16*)p_sWattnA, 32, 1024, 1024, 131072);
    swz_cm<<<64,   256, 0, stream>>>(W_out,  (__bf16*)p_sWout,   32, 70,   70,   16384);
    k_transpose<<<dim3(32, 64), 256, 0, stream>>>(W_attn);
    k_init<<<2048, 256, 0, stream>>>(out);

    // -------- Encoder: 32 steps --------
    for (int t = 0; t < 32; t++) {
        __bf16* hin  = (t & 1) ? hb1 : hb0;
        __bf16* hout = (t & 1) ? hb0 : hb1;
        gru_step<<<dim3(16, 16), 512, 0, stream>>>(
            hin, hout, (__bf16*)p_sWhhe, b_hh_enc,
            (__bf16*)p_sWihe, b_ih_enc, 8, source + t * 512, t);
    }
    // h_enc lands in hb0

    // enc_part = enc_ops @ W_attn[H:2H]^T
    gemm_bt<<<dim3(16, 256), 256, 0, stream>>>(
        (__bf16*)p_enc_ops, 1024, (__bf16*)p_WattnT + 1024, 2048, nullptr,
        p_enc_part, 1024, 1, 1024, 1 << 30);

    // hpart for step 0
    k_hl<<<dim3(18, 16), 256, 0, stream>>>(hb0, b_attn, b_out, -1, out);

    // -------- Decoder: 31 steps --------
    for (int j = 0; j < 31; j++) {
        __bf16* hin  = (j & 1) ? hb1 : hb0;
        __bf16* hout = (j & 1) ? hb0 : hb1;
        k_attn<<<512, 256, 0, stream>>>(j, target, tf, v_attn, out);
        gru_step<<<dim3(16, 16), 512, 0, stream>>>(
            hin, hout, (__bf16*)p_sWhhd, b_hh_dec,
            (__bf16*)p_sWihd, b_ih_dec, 40, nullptr, -1);
        k_hl<<<dim3(18, 16), 256, 0, stream>>>(hout, b_attn, b_out, j + 1, out);
    }
}